// Round 1
// baseline (3701.118 us; speedup 1.0000x reference)
//
#include <hip/hip_runtime.h>
#include <hip/hip_bf16.h>

// Problem constants (from reference)
#define N_NODES   40000
#define N_EDGES   640000
#define F         128      // F_IN == HID == 128
#define N_GRAPHS  64
#define N_CLASSES 10

// ---------------------------------------------------------------------------
// deg count: deg[col[e]] += 1  (deg buffer pre-zeroed; self-loop added later)
__global__ void deg_kernel(const int* __restrict__ col, float* __restrict__ deg) {
    int e = blockIdx.x * 256 + threadIdx.x;
    if (e < N_EDGES) atomicAdd(&deg[col[e]], 1.0f);
}

// dis[v] = rsqrt(deg[v] + 1)   (+1 = self-loop; deg >= 1 so no zero-guard)
__global__ void dis_kernel(float* __restrict__ deg) {
    int v = blockIdx.x * 256 + threadIdx.x;
    if (v < N_NODES) deg[v] = rsqrtf(deg[v] + 1.0f);
}

// ---------------------------------------------------------------------------
// GEMM: out[N,128] = act(A + bias) @ W,  W is [128][128] row-major.
// Block: 256 threads, 64 output rows. LDS: A-tile 32KB + W half-tile 32KB = 64KB.
// Each thread: 8 rows x 4 cols register tile.
__global__ __launch_bounds__(256) void gemm_kernel(
    const float* __restrict__ A, const float* __restrict__ W,
    const float* __restrict__ bias, int dorelu, float* __restrict__ out) {
    __shared__ float As[64 * 128];   // 32 KB
    __shared__ float Ws[64 * 128];   // 32 KB
    const int tid  = threadIdx.x;
    const int row0 = blockIdx.x * 64;

    // Stage A tile (apply bias + relu of previous layer at load time)
#pragma unroll
    for (int j = 0; j < 8; ++j) {
        int fid = tid + j * 256;          // 0..2047 float4s
        int r   = fid >> 5;               // row in tile
        int kq  = (fid & 31) << 2;        // feature quad
        float4 v = *(const float4*)(A + (size_t)(row0 + r) * F + kq);
        if (bias) {
            v.x += bias[kq + 0]; v.y += bias[kq + 1];
            v.z += bias[kq + 2]; v.w += bias[kq + 3];
        }
        if (dorelu) {
            v.x = fmaxf(v.x, 0.f); v.y = fmaxf(v.y, 0.f);
            v.z = fmaxf(v.z, 0.f); v.w = fmaxf(v.w, 0.f);
        }
        *(float4*)(As + r * 128 + kq) = v;
    }

    const int cg    = tid & 31;
    const int rg    = tid >> 5;
    const int c0    = cg << 2;            // 4 output cols
    const int rbase = rg << 3;            // 8 output rows

    float acc[8][4];
#pragma unroll
    for (int i = 0; i < 8; ++i)
#pragma unroll
        for (int j = 0; j < 4; ++j) acc[i][j] = 0.f;

    for (int half = 0; half < 2; ++half) {
        __syncthreads();  // half0: A staged; half1: all Ws reads done
#pragma unroll
        for (int j = 0; j < 8; ++j) {
            int fid = tid + j * 256;      // 0..2047
            int k   = fid >> 5;
            int cq  = (fid & 31) << 2;
            *(float4*)(Ws + k * 128 + cq) =
                *(const float4*)(W + (size_t)(half * 64 + k) * 128 + cq);
        }
        __syncthreads();
        const int kof = half * 64;
#pragma unroll 4
        for (int k = 0; k < 64; ++k) {
            float4 w4 = *(const float4*)(Ws + k * 128 + c0);
#pragma unroll
            for (int i = 0; i < 8; ++i) {
                float a = As[(rbase + i) * 128 + kof + k];
                acc[i][0] += a * w4.x;
                acc[i][1] += a * w4.y;
                acc[i][2] += a * w4.z;
                acc[i][3] += a * w4.w;
            }
        }
    }

#pragma unroll
    for (int i = 0; i < 8; ++i) {
        float4 o = make_float4(acc[i][0], acc[i][1], acc[i][2], acc[i][3]);
        *(float4*)(out + (size_t)(row0 + rbase + i) * F + c0) = o;
    }
}

// ---------------------------------------------------------------------------
// Scatter: AGG[col[e]] += H[row[e]] * dis[row]*dis[col], incl. self-loops.
// 32 lanes per edge, 4 feats/lane (float4 gather, 4 scalar atomics).
__global__ void scatter_kernel(const float* __restrict__ H,
                               const int* __restrict__ row,
                               const int* __restrict__ col,
                               const float* __restrict__ dis,
                               float* __restrict__ AGG) {
    int idx = blockIdx.x * 256 + threadIdx.x;
    int e   = idx >> 5;
    int fq  = (idx & 31) << 2;
    if (e >= N_EDGES + N_NODES) return;
    int r, c;
    if (e < N_EDGES) { r = row[e]; c = col[e]; }
    else             { r = c = e - N_EDGES; }
    float nrm = dis[r] * dis[c];
    float4 h = *(const float4*)(H + (size_t)r * F + fq);
    float* dst = AGG + (size_t)c * F + fq;
    atomicAdd(dst + 0, h.x * nrm);
    atomicAdd(dst + 1, h.y * nrm);
    atomicAdd(dst + 2, h.z * nrm);
    atomicAdd(dst + 3, h.w * nrm);
}

// ---------------------------------------------------------------------------
// Pool: pooled[g][f] += relu(AGG[v][f] + b3[f]); cnt[g] += 1.  batch sorted ->
// run-length accumulate, flush one atomic per graph transition.
#define NODES_PER_POOL_BLOCK 250
__global__ void pool_kernel(const float* __restrict__ AGG,
                            const int* __restrict__ batch,
                            const float* __restrict__ b3,
                            float* __restrict__ pooled, float* __restrict__ cnt) {
    int tid  = threadIdx.x;
    int f    = tid & 127;
    int slot = tid >> 7;                  // 0 or 1
    int base = blockIdx.x * NODES_PER_POOL_BLOCK;
    float bf = b3[f];
    float acc = 0.f, c = 0.f;
    int gcur = -1;
    for (int j = slot; j < NODES_PER_POOL_BLOCK; j += 2) {
        int v = base + j;                 // always < N_NODES (160*250 = 40000)
        int g = batch[v];
        if (g != gcur) {
            if (gcur >= 0) {
                atomicAdd(&pooled[gcur * F + f], acc);
                if (f == 0) atomicAdd(&cnt[gcur], c);
            }
            acc = 0.f; c = 0.f; gcur = g;
        }
        acc += fmaxf(AGG[(size_t)v * F + f] + bf, 0.f);
        c += 1.f;
    }
    if (gcur >= 0) {
        atomicAdd(&pooled[gcur * F + f], acc);
        if (f == 0) atomicAdd(&cnt[gcur], c);
    }
}

// ---------------------------------------------------------------------------
// Head: out[g][c] = (sum_f pooled[g][f] * Wl[f][c]) / max(cnt[g],1) + bl[c]
__global__ void head_kernel(const float* __restrict__ pooled,
                            const float* __restrict__ cnt,
                            const float* __restrict__ Wl,
                            const float* __restrict__ bl,
                            float* __restrict__ out) {
    int tid = threadIdx.x;
    if (tid >= N_GRAPHS * N_CLASSES) return;
    int g = tid / N_CLASSES, c = tid % N_CLASSES;
    float acc = 0.f;
    for (int ff = 0; ff < F; ++ff)
        acc += pooled[g * F + ff] * Wl[ff * N_CLASSES + c];
    out[g * N_CLASSES + c] = acc / fmaxf(cnt[g], 1.f) + bl[c];
}

// ---------------------------------------------------------------------------
extern "C" void kernel_launch(void* const* d_in, const int* in_sizes, int n_in,
                              void* d_out, int out_size, void* d_ws, size_t ws_size,
                              hipStream_t stream) {
    const float* x    = (const float*)d_in[0];
    const int*   ei   = (const int*)d_in[1];     // [2][E]
    const int*   bat  = (const int*)d_in[2];
    const float* W1   = (const float*)d_in[3];
    const float* b1   = (const float*)d_in[4];
    const float* W2   = (const float*)d_in[5];
    const float* b2   = (const float*)d_in[6];
    const float* W3   = (const float*)d_in[7];
    const float* b3   = (const float*)d_in[8];
    const float* Wl   = (const float*)d_in[9];
    const float* bl   = (const float*)d_in[10];
    float* out = (float*)d_out;

    const int* row = ei;                 // edge_index[0]
    const int* col = ei + N_EDGES;       // edge_index[1]

    // Workspace layout (floats)
    float* ws     = (float*)d_ws;
    float* dis    = ws;                               // 40000
    float* H      = dis + N_NODES;                    // 5,120,000
    float* AGG    = H + (size_t)N_NODES * F;          // 5,120,000
    float* pooled = AGG + (size_t)N_NODES * F;        // 8192
    float* cnt    = pooled + N_GRAPHS * F;            // 64

    const size_t featBytes = (size_t)N_NODES * F * sizeof(float);

    // --- normalization coefficients ---
    hipMemsetAsync(dis, 0, N_NODES * sizeof(float), stream);
    deg_kernel<<<N_EDGES / 256, 256, 0, stream>>>(col, dis);
    dis_kernel<<<(N_NODES + 255) / 256, 256, 0, stream>>>(dis);

    const int gemmGrid    = N_NODES / 64;                            // 625
    const int scatterGrid = (N_EDGES + N_NODES) * 32 / 256;          // 85000

    // --- layer 1 ---
    gemm_kernel<<<gemmGrid, 256, 0, stream>>>(x, W1, nullptr, 0, H);
    hipMemsetAsync(AGG, 0, featBytes, stream);
    scatter_kernel<<<scatterGrid, 256, 0, stream>>>(H, row, col, dis, AGG);

    // --- layer 2 (fuses relu(agg + b1) into A staging) ---
    gemm_kernel<<<gemmGrid, 256, 0, stream>>>(AGG, W2, b1, 1, H);
    hipMemsetAsync(AGG, 0, featBytes, stream);
    scatter_kernel<<<scatterGrid, 256, 0, stream>>>(H, row, col, dis, AGG);

    // --- layer 3 ---
    gemm_kernel<<<gemmGrid, 256, 0, stream>>>(AGG, W3, b2, 1, H);
    hipMemsetAsync(AGG, 0, featBytes, stream);
    scatter_kernel<<<scatterGrid, 256, 0, stream>>>(H, row, col, dis, AGG);

    // --- pool (fuses relu(agg + b3)) + head ---
    hipMemsetAsync(pooled, 0, (N_GRAPHS * F + N_GRAPHS) * sizeof(float), stream);
    pool_kernel<<<N_NODES / NODES_PER_POOL_BLOCK, 256, 0, stream>>>(AGG, bat, b3, pooled, cnt);
    head_kernel<<<1, N_GRAPHS * N_CLASSES, 0, stream>>>(pooled, cnt, Wl, bl, out);
}

// Round 2
// 531.663 us; speedup vs baseline: 6.9614x; 6.9614x over previous
//
#include <hip/hip_runtime.h>
#include <hip/hip_bf16.h>

// Problem constants (from reference)
#define N_NODES   40000
#define N_EDGES   640000
#define F         128      // F_IN == HID == 128
#define N_GRAPHS  64
#define N_CLASSES 10

// ---------------------------------------------------------------------------
// CSR build step 1: deg[col[e]] += 1 (int atomics; deg pre-zeroed)
__global__ void count_kernel(const int* __restrict__ col, int* __restrict__ deg) {
    int e = blockIdx.x * 256 + threadIdx.x;
    if (e < N_EDGES) atomicAdd(&deg[col[e]], 1);
}

// CSR build step 2: single-block exclusive scan of deg -> rowptr & cursor,
// plus dis[v] = rsqrt(deg[v] + 1) (self-loop).
#define SCAN_CHUNK 40   // 1024 * 40 = 40960 >= 40000
__global__ __launch_bounds__(1024) void scan_kernel(
    const int* __restrict__ deg, int* __restrict__ rowptr,
    int* __restrict__ cursor, float* __restrict__ dis) {
    __shared__ int sdata[1024];
    const int tid  = threadIdx.x;
    const int base = tid * SCAN_CHUNK;
    int s = 0;
#pragma unroll
    for (int j = 0; j < SCAN_CHUNK; ++j) {
        int idx = base + j;
        if (idx < N_NODES) s += deg[idx];
    }
    sdata[tid] = s;
    __syncthreads();
    // Hillis-Steele inclusive scan over 1024 partials
    for (int off = 1; off < 1024; off <<= 1) {
        int t = (tid >= off) ? sdata[tid - off] : 0;
        __syncthreads();
        sdata[tid] += t;
        __syncthreads();
    }
    int run = sdata[tid] - s;   // exclusive prefix of this thread's chunk
#pragma unroll
    for (int j = 0; j < SCAN_CHUNK; ++j) {
        int idx = base + j;
        if (idx < N_NODES) {
            int d = deg[idx];
            rowptr[idx] = run;
            cursor[idx] = run;
            dis[idx]    = rsqrtf((float)d + 1.0f);
            run += d;
        }
    }
}

// CSR build step 3: csr_src[cursor[col[e]]++] = row[e]
__global__ void fill_kernel(const int* __restrict__ row, const int* __restrict__ col,
                            int* __restrict__ cursor, int* __restrict__ csr_src) {
    int e = blockIdx.x * 256 + threadIdx.x;
    if (e < N_EDGES) {
        int pos = atomicAdd(&cursor[col[e]], 1);
        csr_src[pos] = row[e];
    }
}

// ---------------------------------------------------------------------------
// GEMM: out[N,128] = rscale[r] * (act(A + bias) @ W),  W is [128][128] row-major.
// Block: 256 threads, 64 output rows. LDS: A-tile 32KB + W half-tile 32KB = 64KB.
__global__ __launch_bounds__(256) void gemm_kernel(
    const float* __restrict__ A, const float* __restrict__ W,
    const float* __restrict__ bias, int dorelu,
    const float* __restrict__ rscale, float* __restrict__ out) {
    __shared__ float As[64 * 128];   // 32 KB
    __shared__ float Ws[64 * 128];   // 32 KB
    const int tid  = threadIdx.x;
    const int row0 = blockIdx.x * 64;

#pragma unroll
    for (int j = 0; j < 8; ++j) {
        int fid = tid + j * 256;          // 0..2047 float4s
        int r   = fid >> 5;
        int kq  = (fid & 31) << 2;
        float4 v = *(const float4*)(A + (size_t)(row0 + r) * F + kq);
        if (bias) {
            v.x += bias[kq + 0]; v.y += bias[kq + 1];
            v.z += bias[kq + 2]; v.w += bias[kq + 3];
        }
        if (dorelu) {
            v.x = fmaxf(v.x, 0.f); v.y = fmaxf(v.y, 0.f);
            v.z = fmaxf(v.z, 0.f); v.w = fmaxf(v.w, 0.f);
        }
        *(float4*)(As + r * 128 + kq) = v;
    }

    const int cg    = tid & 31;
    const int rg    = tid >> 5;
    const int c0    = cg << 2;            // 4 output cols
    const int rbase = rg << 3;            // 8 output rows

    float acc[8][4];
#pragma unroll
    for (int i = 0; i < 8; ++i)
#pragma unroll
        for (int j = 0; j < 4; ++j) acc[i][j] = 0.f;

    for (int half = 0; half < 2; ++half) {
        __syncthreads();
#pragma unroll
        for (int j = 0; j < 8; ++j) {
            int fid = tid + j * 256;
            int k   = fid >> 5;
            int cq  = (fid & 31) << 2;
            *(float4*)(Ws + k * 128 + cq) =
                *(const float4*)(W + (size_t)(half * 64 + k) * 128 + cq);
        }
        __syncthreads();
        const int kof = half * 64;
#pragma unroll 4
        for (int k = 0; k < 64; ++k) {
            float4 w4 = *(const float4*)(Ws + k * 128 + c0);
#pragma unroll
            for (int i = 0; i < 8; ++i) {
                float a = As[(rbase + i) * 128 + kof + k];
                acc[i][0] += a * w4.x;
                acc[i][1] += a * w4.y;
                acc[i][2] += a * w4.z;
                acc[i][3] += a * w4.w;
            }
        }
    }

#pragma unroll
    for (int i = 0; i < 8; ++i) {
        float sc = rscale ? rscale[row0 + rbase + i] : 1.0f;
        float4 o = make_float4(acc[i][0] * sc, acc[i][1] * sc,
                               acc[i][2] * sc, acc[i][3] * sc);
        *(float4*)(out + (size_t)(row0 + rbase + i) * F + c0) = o;
    }
}

// ---------------------------------------------------------------------------
// Gather aggregation: one wave per node, 2 floats per lane.
// Hs is pre-scaled by dis[row] (GEMM epilogue), so
//   AGG[v] = dis[v] * ( sum_{e in in(v)} Hs[src] + Hs[v] )
__global__ __launch_bounds__(256) void gather_kernel(
    const float* __restrict__ Hs, const int* __restrict__ csr_src,
    const int* __restrict__ rowptr, const int* __restrict__ deg,
    const float* __restrict__ dis, float* __restrict__ AGG) {
    const int gid  = blockIdx.x * 256 + threadIdx.x;
    const int v    = gid >> 6;
    const int lane = threadIdx.x & 63;
    if (v >= N_NODES) return;

    const int start = rowptr[v];
    const int len   = deg[v];
    const size_t fo = (size_t)lane * 2;

    // self-loop contribution
    float2 acc = *(const float2*)(Hs + (size_t)v * F + fo);

    for (int j0 = 0; j0 < len; j0 += 64) {
        int m = len - j0; if (m > 64) m = 64;
        int nidx = 0;
        if (lane < m) nidx = csr_src[start + j0 + lane];
        int j = 0;
        for (; j + 4 <= m; j += 4) {     // ILP-4: 4 outstanding gathers
            int r0 = __shfl(nidx, j + 0, 64);
            int r1 = __shfl(nidx, j + 1, 64);
            int r2 = __shfl(nidx, j + 2, 64);
            int r3 = __shfl(nidx, j + 3, 64);
            float2 h0 = *(const float2*)(Hs + (size_t)r0 * F + fo);
            float2 h1 = *(const float2*)(Hs + (size_t)r1 * F + fo);
            float2 h2 = *(const float2*)(Hs + (size_t)r2 * F + fo);
            float2 h3 = *(const float2*)(Hs + (size_t)r3 * F + fo);
            acc.x += h0.x; acc.y += h0.y;
            acc.x += h1.x; acc.y += h1.y;
            acc.x += h2.x; acc.y += h2.y;
            acc.x += h3.x; acc.y += h3.y;
        }
        for (; j < m; ++j) {
            int r = __shfl(nidx, j, 64);
            float2 h = *(const float2*)(Hs + (size_t)r * F + fo);
            acc.x += h.x; acc.y += h.y;
        }
    }

    float dc = dis[v];
    acc.x *= dc; acc.y *= dc;
    *(float2*)(AGG + (size_t)v * F + fo) = acc;
}

// ---------------------------------------------------------------------------
// Pool: pooled[g][f] += relu(AGG[v][f] + b3[f]); cnt[g] += 1. batch sorted ->
// run-length accumulate, flush one atomic per graph transition.
#define NODES_PER_POOL_BLOCK 250
__global__ void pool_kernel(const float* __restrict__ AGG,
                            const int* __restrict__ batch,
                            const float* __restrict__ b3,
                            float* __restrict__ pooled, float* __restrict__ cnt) {
    int tid  = threadIdx.x;
    int f    = tid & 127;
    int slot = tid >> 7;
    int base = blockIdx.x * NODES_PER_POOL_BLOCK;
    float bf = b3[f];
    float acc = 0.f, c = 0.f;
    int gcur = -1;
    for (int j = slot; j < NODES_PER_POOL_BLOCK; j += 2) {
        int v = base + j;
        int g = batch[v];
        if (g != gcur) {
            if (gcur >= 0) {
                atomicAdd(&pooled[gcur * F + f], acc);
                if (f == 0) atomicAdd(&cnt[gcur], c);
            }
            acc = 0.f; c = 0.f; gcur = g;
        }
        acc += fmaxf(AGG[(size_t)v * F + f] + bf, 0.f);
        c += 1.f;
    }
    if (gcur >= 0) {
        atomicAdd(&pooled[gcur * F + f], acc);
        if (f == 0) atomicAdd(&cnt[gcur], c);
    }
}

// ---------------------------------------------------------------------------
// Head: out[g][c] = (sum_f pooled[g][f] * Wl[f][c]) / max(cnt[g],1) + bl[c]
__global__ void head_kernel(const float* __restrict__ pooled,
                            const float* __restrict__ cnt,
                            const float* __restrict__ Wl,
                            const float* __restrict__ bl,
                            float* __restrict__ out) {
    int tid = threadIdx.x;
    if (tid >= N_GRAPHS * N_CLASSES) return;
    int g = tid / N_CLASSES, c = tid % N_CLASSES;
    float acc = 0.f;
    for (int ff = 0; ff < F; ++ff)
        acc += pooled[g * F + ff] * Wl[ff * N_CLASSES + c];
    out[g * N_CLASSES + c] = acc / fmaxf(cnt[g], 1.f) + bl[c];
}

// ---------------------------------------------------------------------------
extern "C" void kernel_launch(void* const* d_in, const int* in_sizes, int n_in,
                              void* d_out, int out_size, void* d_ws, size_t ws_size,
                              hipStream_t stream) {
    const float* x    = (const float*)d_in[0];
    const int*   ei   = (const int*)d_in[1];     // [2][E]
    const int*   bat  = (const int*)d_in[2];
    const float* W1   = (const float*)d_in[3];
    const float* b1   = (const float*)d_in[4];
    const float* W2   = (const float*)d_in[5];
    const float* b2   = (const float*)d_in[6];
    const float* W3   = (const float*)d_in[7];
    const float* b3   = (const float*)d_in[8];
    const float* Wl   = (const float*)d_in[9];
    const float* bl   = (const float*)d_in[10];
    float* out = (float*)d_out;

    const int* row = ei;                 // edge_index[0] (source)
    const int* col = ei + N_EDGES;       // edge_index[1] (target)

    // Workspace layout
    float* ws      = (float*)d_ws;
    float* dis     = ws;                               // 40000 f
    float* H       = dis + N_NODES;                    // 5,120,000 f
    float* AGG     = H + (size_t)N_NODES * F;          // 5,120,000 f
    float* pooled  = AGG + (size_t)N_NODES * F;        // 8192 f
    float* cnt     = pooled + N_GRAPHS * F;            // 64 f
    int*   deg     = (int*)(cnt + N_GRAPHS);           // 40000 i
    int*   rowptr  = deg + N_NODES;                    // 40000 i
    int*   cursor  = rowptr + N_NODES;                 // 40000 i
    int*   csr_src = cursor + N_NODES;                 // 640000 i

    const int edgeGrid   = (N_EDGES + 255) / 256;      // 2500
    const int gemmGrid   = N_NODES / 64;               // 625
    const int gatherGrid = (N_NODES * 64) / 256;       // 10000

    // --- CSR build + normalization ---
    hipMemsetAsync(deg, 0, N_NODES * sizeof(int), stream);
    count_kernel<<<edgeGrid, 256, 0, stream>>>(col, deg);
    scan_kernel<<<1, 1024, 0, stream>>>(deg, rowptr, cursor, dis);
    fill_kernel<<<edgeGrid, 256, 0, stream>>>(row, col, cursor, csr_src);

    // --- layer 1 ---
    gemm_kernel<<<gemmGrid, 256, 0, stream>>>(x, W1, nullptr, 0, dis, H);
    gather_kernel<<<gatherGrid, 256, 0, stream>>>(H, csr_src, rowptr, deg, dis, AGG);

    // --- layer 2 (fuses relu(agg + b1) into A staging) ---
    gemm_kernel<<<gemmGrid, 256, 0, stream>>>(AGG, W2, b1, 1, dis, H);
    gather_kernel<<<gatherGrid, 256, 0, stream>>>(H, csr_src, rowptr, deg, dis, AGG);

    // --- layer 3 ---
    gemm_kernel<<<gemmGrid, 256, 0, stream>>>(AGG, W3, b2, 1, dis, H);
    gather_kernel<<<gatherGrid, 256, 0, stream>>>(H, csr_src, rowptr, deg, dis, AGG);

    // --- pool (fuses relu(agg + b3)) + head ---
    hipMemsetAsync(pooled, 0, (N_GRAPHS * F + N_GRAPHS) * sizeof(float), stream);
    pool_kernel<<<N_NODES / NODES_PER_POOL_BLOCK, 256, 0, stream>>>(AGG, bat, b3, pooled, cnt);
    head_kernel<<<1, N_GRAPHS * N_CLASSES, 0, stream>>>(pooled, cnt, Wl, bl, out);
}

// Round 4
// 428.738 us; speedup vs baseline: 8.6326x; 1.2401x over previous
//
#include <hip/hip_runtime.h>
#include <hip/hip_bf16.h>

// Problem constants (from reference)
#define N_NODES   40000
#define N_EDGES   640000
#define F         128      // F_IN == HID == 128
#define N_GRAPHS  64
#define N_CLASSES 10

// ---------------------------------------------------------------------------
// CSR build step 2: single-block scan of deg -> rowptr & cursor, plus
// dis[v] = rsqrt(deg[v] + 1). Coalesced tiles of 4096 (1024 threads x int4),
// wave shuffle-scan + wave0 cross-wave scan. 10 tiles covers 40960 >= 40000.
__global__ __launch_bounds__(1024) void scan_kernel(
    const int* __restrict__ deg, int* __restrict__ rowptr,
    int* __restrict__ cursor, float* __restrict__ dis) {
    __shared__ int wsum[16];       // per-wave inclusive sums
    __shared__ int tile_total_s;
    const int tid  = threadIdx.x;
    const int lane = tid & 63;
    const int wave = tid >> 6;
    int running = 0;

    for (int t = 0; t < 10; ++t) {
        const int base = t * 4096 + tid * 4;
        int4 d = make_int4(0, 0, 0, 0);
        if (base < N_NODES) d = *(const int4*)(deg + base);
        const int sown = d.x + d.y + d.z + d.w;

        // inclusive scan within wave
        int s = sown;
#pragma unroll
        for (int off = 1; off < 64; off <<= 1) {
            int n = __shfl_up(s, off, 64);
            if (lane >= off) s += n;
        }
        if (lane == 63) wsum[wave] = s;
        __syncthreads();

        // wave 0: scan the 16 wave totals
        if (wave == 0) {
            int v = (lane < 16) ? wsum[lane] : 0;
#pragma unroll
            for (int off = 1; off < 16; off <<= 1) {
                int n = __shfl_up(v, off, 64);
                if (lane >= off) v += n;
            }
            if (lane < 16) wsum[lane] = v;       // inclusive
            if (lane == 15) tile_total_s = v;
        }
        __syncthreads();

        int excl = running + (wave ? wsum[wave - 1] : 0) + (s - sown);
        if (base < N_NODES) {
            int4 r;
            r.x = excl;
            r.y = r.x + d.x;
            r.z = r.y + d.y;
            r.w = r.z + d.z;
            *(int4*)(rowptr + base) = r;
            *(int4*)(cursor + base) = r;
            float4 di;
            di.x = rsqrtf((float)d.x + 1.0f);
            di.y = rsqrtf((float)d.y + 1.0f);
            di.z = rsqrtf((float)d.z + 1.0f);
            di.w = rsqrtf((float)d.w + 1.0f);
            *(float4*)(dis + base) = di;
        }
        running += tile_total_s;
        __syncthreads();   // protect wsum/tile_total_s for next tile
    }
}

// CSR build step 3: csr_src[cursor[col[e]]++] = row[e]
__global__ void fill_kernel(const int* __restrict__ row, const int* __restrict__ col,
                            int* __restrict__ cursor, int* __restrict__ csr_src) {
    int e = blockIdx.x * 256 + threadIdx.x;
    if (e < N_EDGES) {
        int pos = atomicAdd(&cursor[col[e]], 1);
        csr_src[pos] = row[e];
    }
}

// ---------------------------------------------------------------------------
// GEMM: out[N,128] = rscale[r] * (act(A + bias) @ W),  W is [128][128] row-major.
// Block: 256 threads, 64 output rows. LDS: A-tile 32KB + W half-tile 32KB = 64KB.
// Optionally fuses the CSR degree count (layer 1): grid is exactly 160000
// threads = 640000/4 edges. NOTE: layer 1 must NOT pass rscale (dis is not
// computed yet at that point) — the layer-1 gather applies dis[src] instead.
__global__ __launch_bounds__(256) void gemm_kernel(
    const float* __restrict__ A, const float* __restrict__ W,
    const float* __restrict__ bias, int dorelu,
    const float* __restrict__ rscale, float* __restrict__ out,
    const int* __restrict__ cnt_col, int* __restrict__ cnt_deg) {
    __shared__ float As[64 * 128];   // 32 KB
    __shared__ float Ws[64 * 128];   // 32 KB
    const int tid  = threadIdx.x;
    const int row0 = blockIdx.x * 64;

    if (cnt_col) {   // fused degree count (deg pre-zeroed)
        int t = (blockIdx.x * 256 + tid) * 4;
#pragma unroll
        for (int j = 0; j < 4; ++j) atomicAdd(&cnt_deg[cnt_col[t + j]], 1);
    }

#pragma unroll
    for (int j = 0; j < 8; ++j) {
        int fid = tid + j * 256;          // 0..2047 float4s
        int r   = fid >> 5;
        int kq  = (fid & 31) << 2;
        float4 v = *(const float4*)(A + (size_t)(row0 + r) * F + kq);
        if (bias) {
            v.x += bias[kq + 0]; v.y += bias[kq + 1];
            v.z += bias[kq + 2]; v.w += bias[kq + 3];
        }
        if (dorelu) {
            v.x = fmaxf(v.x, 0.f); v.y = fmaxf(v.y, 0.f);
            v.z = fmaxf(v.z, 0.f); v.w = fmaxf(v.w, 0.f);
        }
        *(float4*)(As + r * 128 + kq) = v;
    }

    const int cg    = tid & 31;
    const int rg    = tid >> 5;
    const int c0    = cg << 2;            // 4 output cols
    const int rbase = rg << 3;            // 8 output rows

    float acc[8][4];
#pragma unroll
    for (int i = 0; i < 8; ++i)
#pragma unroll
        for (int j = 0; j < 4; ++j) acc[i][j] = 0.f;

    for (int half = 0; half < 2; ++half) {
        __syncthreads();
#pragma unroll
        for (int j = 0; j < 8; ++j) {
            int fid = tid + j * 256;
            int k   = fid >> 5;
            int cq  = (fid & 31) << 2;
            *(float4*)(Ws + k * 128 + cq) =
                *(const float4*)(W + (size_t)(half * 64 + k) * 128 + cq);
        }
        __syncthreads();
        const int kof = half * 64;
#pragma unroll 4
        for (int k = 0; k < 64; ++k) {
            float4 w4 = *(const float4*)(Ws + k * 128 + c0);
#pragma unroll
            for (int i = 0; i < 8; ++i) {
                float a = As[(rbase + i) * 128 + kof + k];
                acc[i][0] += a * w4.x;
                acc[i][1] += a * w4.y;
                acc[i][2] += a * w4.z;
                acc[i][3] += a * w4.w;
            }
        }
    }

#pragma unroll
    for (int i = 0; i < 8; ++i) {
        float sc = rscale ? rscale[row0 + rbase + i] : 1.0f;
        float4 o = make_float4(acc[i][0] * sc, acc[i][1] * sc,
                               acc[i][2] * sc, acc[i][3] * sc);
        *(float4*)(out + (size_t)(row0 + rbase + i) * F + c0) = o;
    }
}

// ---------------------------------------------------------------------------
// Gather aggregation v2: one wave per node; 2 edges per step; float4 per lane
// (half-wave covers a 512B row).
// SCALED=false (layers 2/3): Hs pre-scaled by dis[row] in GEMM epilogue:
//   AGG[v] = dis[v] * ( sum_e Hs[src] + Hs[v] )
// SCALED=true (layer 1): Hs unscaled; apply dis[src] per edge here:
//   AGG[v] = dis[v] * ( sum_e dis[src]*Hs[src] + dis[v]*Hs[v] )
template <bool SCALED>
__global__ __launch_bounds__(256) void gather_kernel(
    const float* __restrict__ Hs, const int* __restrict__ csr_src,
    const int* __restrict__ rowptr, const int* __restrict__ deg,
    const float* __restrict__ dis, float* __restrict__ AGG) {
    const int gid  = blockIdx.x * 256 + threadIdx.x;
    const int v    = gid >> 6;
    if (v >= N_NODES) return;
    const int lane = threadIdx.x & 63;
    const int half = lane >> 5;           // which edge of the pair
    const int q    = (lane & 31) << 2;    // col quad base

    const int start = rowptr[v];
    const int len   = deg[v];

    float4 acc = make_float4(0.f, 0.f, 0.f, 0.f);

    for (int j0 = 0; j0 < len; j0 += 64) {
        int m = len - j0; if (m > 64) m = 64;
        int nidx = (lane < m) ? csr_src[start + j0 + lane] : 0;
        int j = 0;
#pragma unroll 4
        for (; j + 2 <= m; j += 2) {
            int r = __shfl(nidx, j + half, 64);
            float w = SCALED ? dis[r] : 1.0f;      // wave-broadcast load
            float4 h = *(const float4*)(Hs + (size_t)r * F + q);
            acc.x += h.x * w; acc.y += h.y * w;
            acc.z += h.z * w; acc.w += h.w * w;
        }
        if (j < m) {                       // odd tail: half 0 only
            int r = __shfl(nidx, j, 64);
            float w = SCALED ? dis[r] : 1.0f;
            float4 h = *(const float4*)(Hs + (size_t)r * F + q);
            if (half == 0) {
                acc.x += h.x * w; acc.y += h.y * w;
                acc.z += h.z * w; acc.w += h.w * w;
            }
        }
    }

    // combine the two half-wave partials (same cols, lane ^ 32)
    acc.x += __shfl_xor(acc.x, 32, 64);
    acc.y += __shfl_xor(acc.y, 32, 64);
    acc.z += __shfl_xor(acc.z, 32, 64);
    acc.w += __shfl_xor(acc.w, 32, 64);

    if (half == 0) {
        float4 hv = *(const float4*)(Hs + (size_t)v * F + q);  // self-loop
        float dc = dis[v];
        float ws_ = SCALED ? dc : 1.0f;
        float4 o = make_float4((acc.x + hv.x * ws_) * dc, (acc.y + hv.y * ws_) * dc,
                               (acc.z + hv.z * ws_) * dc, (acc.w + hv.w * ws_) * dc);
        *(float4*)(AGG + (size_t)v * F + q) = o;
    }
}

// ---------------------------------------------------------------------------
// Pool: pooled[g][f] += relu(AGG[v][f] + b3[f]); cnt[g] += 1. batch sorted ->
// run-length accumulate, flush one atomic per graph transition.
#define NODES_PER_POOL_BLOCK 250
__global__ void pool_kernel(const float* __restrict__ AGG,
                            const int* __restrict__ batch,
                            const float* __restrict__ b3,
                            float* __restrict__ pooled, float* __restrict__ cnt) {
    int tid  = threadIdx.x;
    int f    = tid & 127;
    int slot = tid >> 7;
    int base = blockIdx.x * NODES_PER_POOL_BLOCK;
    float bf = b3[f];
    float acc = 0.f, c = 0.f;
    int gcur = -1;
    for (int j = slot; j < NODES_PER_POOL_BLOCK; j += 2) {
        int v = base + j;
        int g = batch[v];
        if (g != gcur) {
            if (gcur >= 0) {
                atomicAdd(&pooled[gcur * F + f], acc);
                if (f == 0) atomicAdd(&cnt[gcur], c);
            }
            acc = 0.f; c = 0.f; gcur = g;
        }
        acc += fmaxf(AGG[(size_t)v * F + f] + bf, 0.f);
        c += 1.f;
    }
    if (gcur >= 0) {
        atomicAdd(&pooled[gcur * F + f], acc);
        if (f == 0) atomicAdd(&cnt[gcur], c);
    }
}

// ---------------------------------------------------------------------------
// Head: out[g][c] = (sum_f pooled[g][f] * Wl[f][c]) / max(cnt[g],1) + bl[c]
__global__ void head_kernel(const float* __restrict__ pooled,
                            const float* __restrict__ cnt,
                            const float* __restrict__ Wl,
                            const float* __restrict__ bl,
                            float* __restrict__ out) {
    int tid = threadIdx.x;
    if (tid >= N_GRAPHS * N_CLASSES) return;
    int g = tid / N_CLASSES, c = tid % N_CLASSES;
    float acc = 0.f;
    for (int ff = 0; ff < F; ++ff)
        acc += pooled[g * F + ff] * Wl[ff * N_CLASSES + c];
    out[g * N_CLASSES + c] = acc / fmaxf(cnt[g], 1.f) + bl[c];
}

// ---------------------------------------------------------------------------
extern "C" void kernel_launch(void* const* d_in, const int* in_sizes, int n_in,
                              void* d_out, int out_size, void* d_ws, size_t ws_size,
                              hipStream_t stream) {
    const float* x    = (const float*)d_in[0];
    const int*   ei   = (const int*)d_in[1];     // [2][E]
    const int*   bat  = (const int*)d_in[2];
    const float* W1   = (const float*)d_in[3];
    const float* b1   = (const float*)d_in[4];
    const float* W2   = (const float*)d_in[5];
    const float* b2   = (const float*)d_in[6];
    const float* W3   = (const float*)d_in[7];
    const float* b3   = (const float*)d_in[8];
    const float* Wl   = (const float*)d_in[9];
    const float* bl   = (const float*)d_in[10];
    float* out = (float*)d_out;

    const int* row = ei;                 // edge_index[0] (source)
    const int* col = ei + N_EDGES;       // edge_index[1] (target)

    // Workspace layout
    float* ws      = (float*)d_ws;
    float* dis     = ws;                               // 40000 f
    float* H       = dis + N_NODES;                    // 5,120,000 f
    float* AGG     = H + (size_t)N_NODES * F;          // 5,120,000 f
    float* pooled  = AGG + (size_t)N_NODES * F;        // 8192 f
    float* cnt     = pooled + N_GRAPHS * F;            // 64 f
    int*   deg     = (int*)(cnt + N_GRAPHS);           // 40000 i
    int*   rowptr  = deg + N_NODES;                    // 40000 i
    int*   cursor  = rowptr + N_NODES;                 // 40000 i
    int*   csr_src = cursor + N_NODES;                 // 640000 i

    const int edgeGrid   = (N_EDGES + 255) / 256;      // 2500
    const int gemmGrid   = N_NODES / 64;               // 625
    const int gatherGrid = (N_NODES * 64) / 256;       // 10000

    hipMemsetAsync(deg, 0, N_NODES * sizeof(int), stream);

    // --- layer 1 GEMM (unscaled H, fused degree count), then CSR build ---
    gemm_kernel<<<gemmGrid, 256, 0, stream>>>(x, W1, nullptr, 0, nullptr, H, col, deg);
    scan_kernel<<<1, 1024, 0, stream>>>(deg, rowptr, cursor, dis);
    fill_kernel<<<edgeGrid, 256, 0, stream>>>(row, col, cursor, csr_src);
    gather_kernel<true><<<gatherGrid, 256, 0, stream>>>(H, csr_src, rowptr, deg, dis, AGG);

    // --- layer 2 (fuses relu(agg + b1) into A staging; H pre-scaled by dis) ---
    gemm_kernel<<<gemmGrid, 256, 0, stream>>>(AGG, W2, b1, 1, dis, H, nullptr, nullptr);
    gather_kernel<false><<<gatherGrid, 256, 0, stream>>>(H, csr_src, rowptr, deg, dis, AGG);

    // --- layer 3 ---
    gemm_kernel<<<gemmGrid, 256, 0, stream>>>(AGG, W3, b2, 1, dis, H, nullptr, nullptr);
    gather_kernel<false><<<gatherGrid, 256, 0, stream>>>(H, csr_src, rowptr, deg, dis, AGG);

    // --- pool (fuses relu(agg + b3)) + head ---
    hipMemsetAsync(pooled, 0, (N_GRAPHS * F + N_GRAPHS) * sizeof(float), stream);
    pool_kernel<<<N_NODES / NODES_PER_POOL_BLOCK, 256, 0, stream>>>(AGG, bat, b3, pooled, cnt);
    head_kernel<<<1, N_GRAPHS * N_CLASSES, 0, stream>>>(pooled, cnt, Wl, bl, out);
}

// Round 5
// 325.978 us; speedup vs baseline: 11.3539x; 1.3152x over previous
//
#include <hip/hip_runtime.h>
#include <hip/hip_bf16.h>

// Problem constants (from reference)
#define N_NODES   40000
#define N_EDGES   640000
#define F         128      // F_IN == HID == 128
#define N_GRAPHS  64
#define N_CLASSES 10

typedef short bf16x8 __attribute__((ext_vector_type(8)));
typedef float f32x4  __attribute__((ext_vector_type(4)));

// fp32 -> bf16 with round-to-nearest-even
__device__ __forceinline__ unsigned short f2bf(float f) {
    union { float f; unsigned u; } v; v.f = f;
    unsigned r = v.u + 0x7fffu + ((v.u >> 16) & 1u);
    return (unsigned short)(r >> 16);
}
__device__ __forceinline__ float bflo(unsigned u) { return __uint_as_float(u << 16); }
__device__ __forceinline__ float bfhi(unsigned u) { return __uint_as_float(u & 0xffff0000u); }

// ---------------------------------------------------------------------------
// Precompute transposed bf16 weights: Wt_l[c][k] = bf16(W_l[k][c]), l=0..2.
__global__ void wcvt_kernel(const float* __restrict__ W1, const float* __restrict__ W2,
                            const float* __restrict__ W3, unsigned short* __restrict__ Wt) {
    int idx = blockIdx.x * 256 + threadIdx.x;          // 0 .. 3*16384-1
    int l = idx >> 14;
    int r = idx & 16383;
    int c = r >> 7, k = r & 127;
    const float* W = (l == 0) ? W1 : ((l == 1) ? W2 : W3);
    Wt[idx] = f2bf(W[k * 128 + c]);                    // write coalesced (k fast)
}

// ---------------------------------------------------------------------------
// CSR build step 2: single-block scan of deg -> rowptr & cursor, plus
// dis[v] = rsqrt(deg[v] + 1). Coalesced tiles of 4096 (1024 threads x int4).
__global__ __launch_bounds__(1024) void scan_kernel(
    const int* __restrict__ deg, int* __restrict__ rowptr,
    int* __restrict__ cursor, float* __restrict__ dis) {
    __shared__ int wsum[16];
    __shared__ int tile_total_s;
    const int tid  = threadIdx.x;
    const int lane = tid & 63;
    const int wave = tid >> 6;
    int running = 0;

    for (int t = 0; t < 10; ++t) {
        const int base = t * 4096 + tid * 4;
        int4 d = make_int4(0, 0, 0, 0);
        if (base < N_NODES) d = *(const int4*)(deg + base);
        const int sown = d.x + d.y + d.z + d.w;

        int s = sown;
#pragma unroll
        for (int off = 1; off < 64; off <<= 1) {
            int n = __shfl_up(s, off, 64);
            if (lane >= off) s += n;
        }
        if (lane == 63) wsum[wave] = s;
        __syncthreads();

        if (wave == 0) {
            int v = (lane < 16) ? wsum[lane] : 0;
#pragma unroll
            for (int off = 1; off < 16; off <<= 1) {
                int n = __shfl_up(v, off, 64);
                if (lane >= off) v += n;
            }
            if (lane < 16) wsum[lane] = v;
            if (lane == 15) tile_total_s = v;
        }
        __syncthreads();

        int excl = running + (wave ? wsum[wave - 1] : 0) + (s - sown);
        if (base < N_NODES) {
            int4 r;
            r.x = excl;
            r.y = r.x + d.x;
            r.z = r.y + d.y;
            r.w = r.z + d.z;
            *(int4*)(rowptr + base) = r;
            *(int4*)(cursor + base) = r;
            float4 di;
            di.x = rsqrtf((float)d.x + 1.0f);
            di.y = rsqrtf((float)d.y + 1.0f);
            di.z = rsqrtf((float)d.z + 1.0f);
            di.w = rsqrtf((float)d.w + 1.0f);
            *(float4*)(dis + base) = di;
        }
        running += tile_total_s;
        __syncthreads();
    }
}

// CSR build step 3: csr_src[cursor[col[e]]++] = row[e]
__global__ void fill_kernel(const int* __restrict__ row, const int* __restrict__ col,
                            int* __restrict__ cursor, int* __restrict__ csr_src) {
    int e = blockIdx.x * 256 + threadIdx.x;
    if (e < N_EDGES) {
        int pos = atomicAdd(&cursor[col[e]], 1);
        csr_src[pos] = row[e];
    }
}

// ---------------------------------------------------------------------------
// MFMA GEMM: Hb[r][c] = bf16( scale_r * relu?(A[r][:] + bias) @ W )
// A fp32 [N][128]; Wt = precomputed W^T bf16 [128 c][128 k].
// Block: 256 threads / 4 waves, 64 rows. Wave w: rows [w*16,w*16+16), all 128 cols
// as 8 MFMA 16x16x32 tiles. LDS 52 KB -> 3 blocks/CU.
// Fragment maps (verified m89/m92/m120): A: m=lane&15, k=quad*8+j;
// B^T: n=lane&15, k=quad*8+j; D: col=lane&15, row=quad*4+reg.
#define APITCH 136   // bf16 units; 272 B rows: 16B-aligned frags, bank-spread
template<bool RELU, bool SCALE, bool COUNT>
__global__ __launch_bounds__(256) void gemm_mfma(
    const float* __restrict__ A, const unsigned short* __restrict__ Wt,
    const float* __restrict__ bias, const float* __restrict__ dis,
    unsigned short* __restrict__ Hb,
    const int* __restrict__ cnt_col, int* __restrict__ cnt_deg) {
    __shared__ unsigned short As[64 * APITCH];    // 17408 B
    __shared__ unsigned short Ws[128 * APITCH];   // 34816 B
    const int tid  = threadIdx.x;
    const int row0 = blockIdx.x * 64;

    if (COUNT) {   // fused degree count for CSR build (deg pre-zeroed)
        int t = (blockIdx.x * 256 + tid) * 4;
#pragma unroll
        for (int j = 0; j < 4; ++j) atomicAdd(&cnt_deg[cnt_col[t + j]], 1);
    }

    // Stage Wt (bf16, 32768 B = 2048 uint4) -> Ws
    {
        const uint4* src = (const uint4*)Wt;
#pragma unroll
        for (int j = 0; j < 8; ++j) {
            int c4 = tid + j * 256;        // 0..2047; 16 uint4 per 128-bf16 row
            int c  = c4 >> 4;
            int o  = c4 & 15;
            *(uint4*)(Ws + c * APITCH + o * 8) = src[c4];
        }
    }
    // Stage A (fp32 -> bias/relu -> bf16) -> As
#pragma unroll
    for (int j = 0; j < 8; ++j) {
        int c4 = tid + j * 256;            // 0..2047; 32 float4 per row
        int r  = c4 >> 5;
        int o  = (c4 & 31) << 2;
        float4 v = *(const float4*)(A + (size_t)(row0 + r) * F + o);
        if (bias) {
            v.x += bias[o + 0]; v.y += bias[o + 1];
            v.z += bias[o + 2]; v.w += bias[o + 3];
        }
        if (RELU) {
            v.x = fmaxf(v.x, 0.f); v.y = fmaxf(v.y, 0.f);
            v.z = fmaxf(v.z, 0.f); v.w = fmaxf(v.w, 0.f);
        }
        uint2 p;
        p.x = (unsigned)f2bf(v.x) | ((unsigned)f2bf(v.y) << 16);
        p.y = (unsigned)f2bf(v.z) | ((unsigned)f2bf(v.w) << 16);
        *(uint2*)(As + r * APITCH + o) = p;
    }
    __syncthreads();

    const int lane = tid & 63;
    const int wave = tid >> 6;
    const int m16  = lane & 15;
    const int quad = lane >> 4;

    f32x4 acc[8];
#pragma unroll
    for (int t = 0; t < 8; ++t) acc[t] = (f32x4)(0.0f);

#pragma unroll
    for (int ks = 0; ks < 128; ks += 32) {
        bf16x8 a = *(const bf16x8*)(As + (wave * 16 + m16) * APITCH + ks + quad * 8);
#pragma unroll
        for (int t = 0; t < 8; ++t) {
            bf16x8 b = *(const bf16x8*)(Ws + (t * 16 + m16) * APITCH + ks + quad * 8);
            acc[t] = __builtin_amdgcn_mfma_f32_16x16x32_bf16(a, b, acc[t], 0, 0, 0);
        }
    }

    // Epilogue: D row = quad*4+reg, col = t*16 + m16; optional dis[row] scale.
    const int rbase = row0 + wave * 16 + quad * 4;
    float sc[4];
#pragma unroll
    for (int rg = 0; rg < 4; ++rg) sc[rg] = SCALE ? dis[rbase + rg] : 1.0f;
#pragma unroll
    for (int t = 0; t < 8; ++t) {
        int col = t * 16 + m16;
#pragma unroll
        for (int rg = 0; rg < 4; ++rg)
            Hb[(size_t)(rbase + rg) * F + col] = f2bf(acc[t][rg] * sc[rg]);
    }
}

// ---------------------------------------------------------------------------
// Gather aggregation v3 (bf16 H): one wave per node, 4 edges per step,
// uint4 (8 bf16) per lane, fp32 accumulate, quad shfl_xor reduction.
// SCALED=false: Hb pre-scaled by dis[row]:  AGG[v] = dis[v]*(sum Hb[src] + Hb[v])
// SCALED=true : AGG[v] = dis[v]*(sum dis[src]*Hb[src] + dis[v]*Hb[v])
template <bool SCALED>
__global__ __launch_bounds__(256) void gather_kernel(
    const unsigned short* __restrict__ Hb, const int* __restrict__ csr_src,
    const int* __restrict__ rowptr, const int* __restrict__ deg,
    const float* __restrict__ dis, float* __restrict__ AGG) {
    const int gid  = blockIdx.x * 256 + threadIdx.x;
    const int v    = gid >> 6;
    if (v >= N_NODES) return;
    const int lane = threadIdx.x & 63;
    const int part = lane & 15;          // 16B chunk of the 256B row
    const int quad = lane >> 4;          // which edge of the 4

    const int start = rowptr[v];
    const int len   = deg[v];
    const uint4* Hv = (const uint4*)Hb;  // 16 uint4 per row

    float acc[8];
#pragma unroll
    for (int i = 0; i < 8; ++i) acc[i] = 0.f;

    for (int j0 = 0; j0 < len; j0 += 64) {
        int m = len - j0; if (m > 64) m = 64;
        int nidx = (lane < m) ? csr_src[start + j0 + lane] : 0;
        for (int j = 0; j < m; j += 4) {
            int  sl    = j + quad;
            bool valid = sl < m;
            int  r     = __shfl(nidx, valid ? sl : 0, 64);
            float w    = valid ? (SCALED ? dis[r] : 1.0f) : 0.0f;
            uint4 h = Hv[(size_t)r * 16 + part];
            acc[0] = fmaf(bflo(h.x), w, acc[0]); acc[1] = fmaf(bfhi(h.x), w, acc[1]);
            acc[2] = fmaf(bflo(h.y), w, acc[2]); acc[3] = fmaf(bfhi(h.y), w, acc[3]);
            acc[4] = fmaf(bflo(h.z), w, acc[4]); acc[5] = fmaf(bfhi(h.z), w, acc[5]);
            acc[6] = fmaf(bflo(h.w), w, acc[6]); acc[7] = fmaf(bfhi(h.w), w, acc[7]);
        }
    }

    // combine the 4 edge-slots (same cols at lane^16, lane^32)
#pragma unroll
    for (int i = 0; i < 8; ++i) {
        acc[i] += __shfl_xor(acc[i], 16, 64);
        acc[i] += __shfl_xor(acc[i], 32, 64);
    }

    if (quad == 0) {
        float dc  = dis[v];
        float ws_ = SCALED ? dc : 1.0f;
        uint4 h = Hv[(size_t)v * 16 + part];            // self-loop
        acc[0] = fmaf(bflo(h.x), ws_, acc[0]); acc[1] = fmaf(bfhi(h.x), ws_, acc[1]);
        acc[2] = fmaf(bflo(h.y), ws_, acc[2]); acc[3] = fmaf(bfhi(h.y), ws_, acc[3]);
        acc[4] = fmaf(bflo(h.z), ws_, acc[4]); acc[5] = fmaf(bfhi(h.z), ws_, acc[5]);
        acc[6] = fmaf(bflo(h.w), ws_, acc[6]); acc[7] = fmaf(bfhi(h.w), ws_, acc[7]);
        float* dst = AGG + (size_t)v * F + part * 8;
        *(float4*)(dst + 0) = make_float4(acc[0] * dc, acc[1] * dc, acc[2] * dc, acc[3] * dc);
        *(float4*)(dst + 4) = make_float4(acc[4] * dc, acc[5] * dc, acc[6] * dc, acc[7] * dc);
    }
}

// ---------------------------------------------------------------------------
// Pool: pooled[g][f] += relu(AGG[v][f] + b3[f]); cnt[g] += 1. batch sorted ->
// run-length accumulate, flush one atomic per graph transition.
#define NODES_PER_POOL_BLOCK 250
__global__ void pool_kernel(const float* __restrict__ AGG,
                            const int* __restrict__ batch,
                            const float* __restrict__ b3,
                            float* __restrict__ pooled, float* __restrict__ cnt) {
    int tid  = threadIdx.x;
    int f    = tid & 127;
    int slot = tid >> 7;
    int base = blockIdx.x * NODES_PER_POOL_BLOCK;
    float bf = b3[f];
    float acc = 0.f, c = 0.f;
    int gcur = -1;
    for (int j = slot; j < NODES_PER_POOL_BLOCK; j += 2) {
        int v = base + j;
        int g = batch[v];
        if (g != gcur) {
            if (gcur >= 0) {
                atomicAdd(&pooled[gcur * F + f], acc);
                if (f == 0) atomicAdd(&cnt[gcur], c);
            }
            acc = 0.f; c = 0.f; gcur = g;
        }
        acc += fmaxf(AGG[(size_t)v * F + f] + bf, 0.f);
        c += 1.f;
    }
    if (gcur >= 0) {
        atomicAdd(&pooled[gcur * F + f], acc);
        if (f == 0) atomicAdd(&cnt[gcur], c);
    }
}

// ---------------------------------------------------------------------------
// Head: out[g][c] = (sum_f pooled[g][f] * Wl[f][c]) / max(cnt[g],1) + bl[c]
__global__ void head_kernel(const float* __restrict__ pooled,
                            const float* __restrict__ cnt,
                            const float* __restrict__ Wl,
                            const float* __restrict__ bl,
                            float* __restrict__ out) {
    int tid = threadIdx.x;
    if (tid >= N_GRAPHS * N_CLASSES) return;
    int g = tid / N_CLASSES, c = tid % N_CLASSES;
    float acc = 0.f;
    for (int ff = 0; ff < F; ++ff)
        acc += pooled[g * F + ff] * Wl[ff * N_CLASSES + c];
    out[g * N_CLASSES + c] = acc / fmaxf(cnt[g], 1.f) + bl[c];
}

// ---------------------------------------------------------------------------
extern "C" void kernel_launch(void* const* d_in, const int* in_sizes, int n_in,
                              void* d_out, int out_size, void* d_ws, size_t ws_size,
                              hipStream_t stream) {
    const float* x    = (const float*)d_in[0];
    const int*   ei   = (const int*)d_in[1];     // [2][E]
    const int*   bat  = (const int*)d_in[2];
    const float* W1   = (const float*)d_in[3];
    const float* b1   = (const float*)d_in[4];
    const float* W2   = (const float*)d_in[5];
    const float* b2   = (const float*)d_in[6];
    const float* W3   = (const float*)d_in[7];
    const float* b3   = (const float*)d_in[8];
    const float* Wl   = (const float*)d_in[9];
    const float* bl   = (const float*)d_in[10];
    float* out = (float*)d_out;

    const int* row = ei;                 // edge_index[0] (source)
    const int* col = ei + N_EDGES;       // edge_index[1] (target)

    // Workspace layout (16B-aligned chunks)
    float*          ws      = (float*)d_ws;
    float*          dis     = ws;                                     // 40000 f
    unsigned short* Hb      = (unsigned short*)(dis + N_NODES);       // 5.12M bf16
    float*          AGG     = (float*)(Hb + (size_t)N_NODES * F);     // 5.12M f
    float*          pooled  = AGG + (size_t)N_NODES * F;              // 8192 f
    float*          cnt     = pooled + N_GRAPHS * F;                  // 64 f
    int*            deg     = (int*)(cnt + N_GRAPHS);                 // 40000 i
    int*            rowptr  = deg + N_NODES;                          // 40000 i
    int*            cursor  = rowptr + N_NODES;                       // 40000 i
    int*            csr_src = cursor + N_NODES;                       // 640000 i
    unsigned short* Wtb     = (unsigned short*)(csr_src + N_EDGES);   // 3*16384 bf16

    const int edgeGrid   = (N_EDGES + 255) / 256;      // 2500
    const int gemmGrid   = N_NODES / 64;               // 625
    const int gatherGrid = (N_NODES * 64) / 256;       // 10000

    hipMemsetAsync(deg, 0, N_NODES * sizeof(int), stream);
    wcvt_kernel<<<192, 256, 0, stream>>>(W1, W2, W3, Wtb);

    // --- layer 1 GEMM (unscaled bf16 H, fused degree count), then CSR build ---
    gemm_mfma<false, false, true><<<gemmGrid, 256, 0, stream>>>(
        x, Wtb, nullptr, nullptr, Hb, col, deg);
    scan_kernel<<<1, 1024, 0, stream>>>(deg, rowptr, cursor, dis);
    fill_kernel<<<edgeGrid, 256, 0, stream>>>(row, col, cursor, csr_src);
    gather_kernel<true><<<gatherGrid, 256, 0, stream>>>(Hb, csr_src, rowptr, deg, dis, AGG);

    // --- layer 2 (relu(agg+b1) fused into staging; H pre-scaled by dis) ---
    gemm_mfma<true, true, false><<<gemmGrid, 256, 0, stream>>>(
        AGG, Wtb + 16384, b1, dis, Hb, nullptr, nullptr);
    gather_kernel<false><<<gatherGrid, 256, 0, stream>>>(Hb, csr_src, rowptr, deg, dis, AGG);

    // --- layer 3 ---
    gemm_mfma<true, true, false><<<gemmGrid, 256, 0, stream>>>(
        AGG, Wtb + 32768, b2, dis, Hb, nullptr, nullptr);
    gather_kernel<false><<<gatherGrid, 256, 0, stream>>>(Hb, csr_src, rowptr, deg, dis, AGG);

    // --- pool (fuses relu(agg + b3)) + head ---
    hipMemsetAsync(pooled, 0, (N_GRAPHS * F + N_GRAPHS) * sizeof(float), stream);
    pool_kernel<<<N_NODES / NODES_PER_POOL_BLOCK, 256, 0, stream>>>(AGG, bat, b3, pooled, cnt);
    head_kernel<<<1, N_GRAPHS * N_CLASSES, 0, stream>>>(pooled, cnt, Wl, bl, out);
}

// Round 6
// 307.765 us; speedup vs baseline: 12.0258x; 1.0592x over previous
//
#include <hip/hip_runtime.h>
#include <hip/hip_bf16.h>

// Problem constants (from reference)
#define N_NODES   40000
#define N_EDGES   640000
#define F         128      // F_IN == HID == 128
#define N_GRAPHS  64
#define N_CLASSES 10

typedef short bf16x8 __attribute__((ext_vector_type(8)));
typedef float f32x4  __attribute__((ext_vector_type(4)));

// fp32 -> bf16 with round-to-nearest-even
__device__ __forceinline__ unsigned short f2bf(float f) {
    union { float f; unsigned u; } v; v.f = f;
    unsigned r = v.u + 0x7fffu + ((v.u >> 16) & 1u);
    return (unsigned short)(r >> 16);
}
__device__ __forceinline__ float bflo(unsigned u) { return __uint_as_float(u << 16); }
__device__ __forceinline__ float bfhi(unsigned u) { return __uint_as_float(u & 0xffff0000u); }

// ---------------------------------------------------------------------------
// Precompute transposed bf16 weights: Wt_l[c][k] = bf16(W_l[k][c]), l=0..2.
__global__ void wcvt_kernel(const float* __restrict__ W1, const float* __restrict__ W2,
                            const float* __restrict__ W3, unsigned short* __restrict__ Wt) {
    int idx = blockIdx.x * 256 + threadIdx.x;          // 0 .. 3*16384-1
    int l = idx >> 14;
    int r = idx & 16383;
    int c = r >> 7, k = r & 127;
    const float* W = (l == 0) ? W1 : ((l == 1) ? W2 : W3);
    Wt[idx] = f2bf(W[k * 128 + c]);                    // write coalesced (k fast)
}

// ---------------------------------------------------------------------------
// CSR build step 2: single-block scan of deg -> rowptr & cursor, plus
// dis[v] = rsqrt(deg[v] + 1). Coalesced tiles of 4096 (1024 threads x int4).
__global__ __launch_bounds__(1024) void scan_kernel(
    const int* __restrict__ deg, int* __restrict__ rowptr,
    int* __restrict__ cursor, float* __restrict__ dis) {
    __shared__ int wsum[16];
    __shared__ int tile_total_s;
    const int tid  = threadIdx.x;
    const int lane = tid & 63;
    const int wave = tid >> 6;
    int running = 0;

    for (int t = 0; t < 10; ++t) {
        const int base = t * 4096 + tid * 4;
        int4 d = make_int4(0, 0, 0, 0);
        if (base < N_NODES) d = *(const int4*)(deg + base);
        const int sown = d.x + d.y + d.z + d.w;

        int s = sown;
#pragma unroll
        for (int off = 1; off < 64; off <<= 1) {
            int n = __shfl_up(s, off, 64);
            if (lane >= off) s += n;
        }
        if (lane == 63) wsum[wave] = s;
        __syncthreads();

        if (wave == 0) {
            int v = (lane < 16) ? wsum[lane] : 0;
#pragma unroll
            for (int off = 1; off < 16; off <<= 1) {
                int n = __shfl_up(v, off, 64);
                if (lane >= off) v += n;
            }
            if (lane < 16) wsum[lane] = v;
            if (lane == 15) tile_total_s = v;
        }
        __syncthreads();

        int excl = running + (wave ? wsum[wave - 1] : 0) + (s - sown);
        if (base < N_NODES) {
            int4 r;
            r.x = excl;
            r.y = r.x + d.x;
            r.z = r.y + d.y;
            r.w = r.z + d.z;
            *(int4*)(rowptr + base) = r;
            *(int4*)(cursor + base) = r;
            float4 di;
            di.x = rsqrtf((float)d.x + 1.0f);
            di.y = rsqrtf((float)d.y + 1.0f);
            di.z = rsqrtf((float)d.z + 1.0f);
            di.w = rsqrtf((float)d.w + 1.0f);
            *(float4*)(dis + base) = di;
        }
        running += tile_total_s;
        __syncthreads();
    }
}

// CSR build step 3: csr_src[cursor[col[e]]++] = row[e]
__global__ void fill_kernel(const int* __restrict__ row, const int* __restrict__ col,
                            int* __restrict__ cursor, int* __restrict__ csr_src) {
    int e = blockIdx.x * 256 + threadIdx.x;
    if (e < N_EDGES) {
        int pos = atomicAdd(&cursor[col[e]], 1);
        csr_src[pos] = row[e];
    }
}

// ---------------------------------------------------------------------------
// MFMA GEMM: Hb[r][c] = bf16( scale_r * relu?(A[r][:] + bias) @ W )
// A fp32 [N][128]; Wt = precomputed W^T bf16 [128 c][128 k].
// Block: 256 threads / 4 waves, 64 rows. Wave w: rows [w*16,w*16+16), all 128 cols
// as 8 MFMA 16x16x32 tiles. LDS 52 KB -> 3 blocks/CU.
// Fragment maps (verified m89/m92/m120): A: m=lane&15, k=quad*8+j;
// B^T: n=lane&15, k=quad*8+j; D: col=lane&15, row=quad*4+reg.
#define APITCH 136   // bf16 units; 272 B rows: 16B-aligned frags, bank-spread
template<bool RELU, bool SCALE, bool COUNT>
__global__ __launch_bounds__(256) void gemm_mfma(
    const float* __restrict__ A, const unsigned short* __restrict__ Wt,
    const float* __restrict__ bias, const float* __restrict__ dis,
    unsigned short* __restrict__ Hb,
    const int* __restrict__ cnt_col, int* __restrict__ cnt_deg) {
    __shared__ unsigned short As[64 * APITCH];    // 17408 B
    __shared__ unsigned short Ws[128 * APITCH];   // 34816 B
    const int tid  = threadIdx.x;
    const int row0 = blockIdx.x * 64;

    if (COUNT) {   // fused degree count for CSR build (deg pre-zeroed)
        int t = (blockIdx.x * 256 + tid) * 4;
#pragma unroll
        for (int j = 0; j < 4; ++j) atomicAdd(&cnt_deg[cnt_col[t + j]], 1);
    }

    // Stage Wt (bf16, 32768 B = 2048 uint4) -> Ws
    {
        const uint4* src = (const uint4*)Wt;
#pragma unroll
        for (int j = 0; j < 8; ++j) {
            int c4 = tid + j * 256;        // 0..2047; 16 uint4 per 128-bf16 row
            int c  = c4 >> 4;
            int o  = c4 & 15;
            *(uint4*)(Ws + c * APITCH + o * 8) = src[c4];
        }
    }
    // Stage A (fp32 -> bias/relu -> bf16) -> As
#pragma unroll
    for (int j = 0; j < 8; ++j) {
        int c4 = tid + j * 256;            // 0..2047; 32 float4 per row
        int r  = c4 >> 5;
        int o  = (c4 & 31) << 2;
        float4 v = *(const float4*)(A + (size_t)(row0 + r) * F + o);
        if (bias) {
            v.x += bias[o + 0]; v.y += bias[o + 1];
            v.z += bias[o + 2]; v.w += bias[o + 3];
        }
        if (RELU) {
            v.x = fmaxf(v.x, 0.f); v.y = fmaxf(v.y, 0.f);
            v.z = fmaxf(v.z, 0.f); v.w = fmaxf(v.w, 0.f);
        }
        uint2 p;
        p.x = (unsigned)f2bf(v.x) | ((unsigned)f2bf(v.y) << 16);
        p.y = (unsigned)f2bf(v.z) | ((unsigned)f2bf(v.w) << 16);
        *(uint2*)(As + r * APITCH + o) = p;
    }
    __syncthreads();

    const int lane = tid & 63;
    const int wave = tid >> 6;
    const int m16  = lane & 15;
    const int quad = lane >> 4;

    f32x4 acc[8];
#pragma unroll
    for (int t = 0; t < 8; ++t) acc[t] = (f32x4)(0.0f);

#pragma unroll
    for (int ks = 0; ks < 128; ks += 32) {
        bf16x8 a = *(const bf16x8*)(As + (wave * 16 + m16) * APITCH + ks + quad * 8);
#pragma unroll
        for (int t = 0; t < 8; ++t) {
            bf16x8 b = *(const bf16x8*)(Ws + (t * 16 + m16) * APITCH + ks + quad * 8);
            acc[t] = __builtin_amdgcn_mfma_f32_16x16x32_bf16(a, b, acc[t], 0, 0, 0);
        }
    }

    // Epilogue: D row = quad*4+reg, col = t*16 + m16; optional dis[row] scale.
    const int rbase = row0 + wave * 16 + quad * 4;
    float sc[4];
#pragma unroll
    for (int rg = 0; rg < 4; ++rg) sc[rg] = SCALE ? dis[rbase + rg] : 1.0f;
#pragma unroll
    for (int t = 0; t < 8; ++t) {
        int col = t * 16 + m16;
#pragma unroll
        for (int rg = 0; rg < 4; ++rg)
            Hb[(size_t)(rbase + rg) * F + col] = f2bf(acc[t][rg] * sc[rg]);
    }
}

// ---------------------------------------------------------------------------
// Gather aggregation v4 (bf16 H): one wave per node; 8 edges per main step
// (2 independent uint4 gathers in flight per lane), 4-edge masked tail;
// fp32 accumulate, quad shfl_xor reduction.
// SCALED=false: Hb pre-scaled by dis[row]:  AGG[v] = dis[v]*(sum Hb[src] + Hb[v])
// SCALED=true : AGG[v] = dis[v]*(sum dis[src]*Hb[src] + dis[v]*Hb[v])
template <bool SCALED>
__global__ __launch_bounds__(256) void gather_kernel(
    const unsigned short* __restrict__ Hb, const int* __restrict__ csr_src,
    const int* __restrict__ rowptr, const int* __restrict__ deg,
    const float* __restrict__ dis, float* __restrict__ AGG) {
    const int gid  = blockIdx.x * 256 + threadIdx.x;
    const int v    = gid >> 6;
    if (v >= N_NODES) return;
    const int lane = threadIdx.x & 63;
    const int part = lane & 15;          // 16B chunk of the 256B row
    const int quad = lane >> 4;          // edge slot within group of 4

    const int start = rowptr[v];
    const int len   = deg[v];
    const uint4* Hv = (const uint4*)Hb;  // 16 uint4 per row

    float acc[8];
#pragma unroll
    for (int i = 0; i < 8; ++i) acc[i] = 0.f;

    for (int j0 = 0; j0 < len; j0 += 64) {
        int m = len - j0; if (m > 64) m = 64;
        int nidx = (lane < m) ? csr_src[start + j0 + lane] : 0;
        int j = 0;
        // main: 8 edges per iteration, two gathers in flight
        for (; j + 8 <= m; j += 8) {
            int r0 = __shfl(nidx, j + quad, 64);
            int r1 = __shfl(nidx, j + 4 + quad, 64);
            float w0 = SCALED ? dis[r0] : 1.0f;
            float w1 = SCALED ? dis[r1] : 1.0f;
            uint4 h0 = Hv[(size_t)r0 * 16 + part];
            uint4 h1 = Hv[(size_t)r1 * 16 + part];
            acc[0] = fmaf(bflo(h0.x), w0, acc[0]); acc[1] = fmaf(bfhi(h0.x), w0, acc[1]);
            acc[2] = fmaf(bflo(h0.y), w0, acc[2]); acc[3] = fmaf(bfhi(h0.y), w0, acc[3]);
            acc[4] = fmaf(bflo(h0.z), w0, acc[4]); acc[5] = fmaf(bfhi(h0.z), w0, acc[5]);
            acc[6] = fmaf(bflo(h0.w), w0, acc[6]); acc[7] = fmaf(bfhi(h0.w), w0, acc[7]);
            acc[0] = fmaf(bflo(h1.x), w1, acc[0]); acc[1] = fmaf(bfhi(h1.x), w1, acc[1]);
            acc[2] = fmaf(bflo(h1.y), w1, acc[2]); acc[3] = fmaf(bfhi(h1.y), w1, acc[3]);
            acc[4] = fmaf(bflo(h1.z), w1, acc[4]); acc[5] = fmaf(bfhi(h1.z), w1, acc[5]);
            acc[6] = fmaf(bflo(h1.w), w1, acc[6]); acc[7] = fmaf(bfhi(h1.w), w1, acc[7]);
        }
        // tail: 4 edges at a time, masked
        for (; j < m; j += 4) {
            int  sl    = j + quad;
            bool valid = sl < m;
            int  r     = __shfl(nidx, valid ? sl : 0, 64);
            float w    = valid ? (SCALED ? dis[r] : 1.0f) : 0.0f;
            uint4 h = Hv[(size_t)r * 16 + part];
            acc[0] = fmaf(bflo(h.x), w, acc[0]); acc[1] = fmaf(bfhi(h.x), w, acc[1]);
            acc[2] = fmaf(bflo(h.y), w, acc[2]); acc[3] = fmaf(bfhi(h.y), w, acc[3]);
            acc[4] = fmaf(bflo(h.z), w, acc[4]); acc[5] = fmaf(bfhi(h.z), w, acc[5]);
            acc[6] = fmaf(bflo(h.w), w, acc[6]); acc[7] = fmaf(bfhi(h.w), w, acc[7]);
        }
    }

    // combine the 4 edge-slots (same cols at lane^16, lane^32)
#pragma unroll
    for (int i = 0; i < 8; ++i) {
        acc[i] += __shfl_xor(acc[i], 16, 64);
        acc[i] += __shfl_xor(acc[i], 32, 64);
    }

    if (quad == 0) {
        float dc  = dis[v];
        float ws_ = SCALED ? dc : 1.0f;
        uint4 h = Hv[(size_t)v * 16 + part];            // self-loop
        acc[0] = fmaf(bflo(h.x), ws_, acc[0]); acc[1] = fmaf(bfhi(h.x), ws_, acc[1]);
        acc[2] = fmaf(bflo(h.y), ws_, acc[2]); acc[3] = fmaf(bfhi(h.y), ws_, acc[3]);
        acc[4] = fmaf(bflo(h.z), ws_, acc[4]); acc[5] = fmaf(bfhi(h.z), ws_, acc[5]);
        acc[6] = fmaf(bflo(h.w), ws_, acc[6]); acc[7] = fmaf(bfhi(h.w), ws_, acc[7]);
        float* dst = AGG + (size_t)v * F + part * 8;
        *(float4*)(dst + 0) = make_float4(acc[0] * dc, acc[1] * dc, acc[2] * dc, acc[3] * dc);
        *(float4*)(dst + 4) = make_float4(acc[4] * dc, acc[5] * dc, acc[6] * dc, acc[7] * dc);
    }
}

// ---------------------------------------------------------------------------
// Pool v2: 400 blocks x 100 nodes; 8 row-slots x 32 lanes x float4.
// pooled[g][f] += relu(AGG[v][f] + b3[f]); cnt[g] += 1. batch sorted ->
// per-slot run-length accumulate (slot's g non-decreasing), flush on change.
#define POOL_NODES 100
__global__ __launch_bounds__(256) void pool_kernel(
    const float* __restrict__ AGG, const int* __restrict__ batch,
    const float* __restrict__ b3,
    float* __restrict__ pooled, float* __restrict__ cnt) {
    const int tid  = threadIdx.x;
    const int f4   = (tid & 31) << 2;     // float4 column
    const int slot = tid >> 5;            // 0..7
    const int base = blockIdx.x * POOL_NODES;
    const float4 bf = *(const float4*)(b3 + f4);

    float4 acc = make_float4(0.f, 0.f, 0.f, 0.f);
    float c = 0.f;
    int gcur = -1;
    for (int j = slot; j < POOL_NODES; j += 8) {
        int v = base + j;                 // 400*100 = 40000, always in range
        int g = batch[v];
        if (g != gcur) {
            if (gcur >= 0) {
                float* dst = pooled + gcur * F + f4;
                atomicAdd(dst + 0, acc.x); atomicAdd(dst + 1, acc.y);
                atomicAdd(dst + 2, acc.z); atomicAdd(dst + 3, acc.w);
                if (f4 == 0) atomicAdd(&cnt[gcur], c);
            }
            acc = make_float4(0.f, 0.f, 0.f, 0.f); c = 0.f; gcur = g;
        }
        float4 a = *(const float4*)(AGG + (size_t)v * F + f4);
        acc.x += fmaxf(a.x + bf.x, 0.f);
        acc.y += fmaxf(a.y + bf.y, 0.f);
        acc.z += fmaxf(a.z + bf.z, 0.f);
        acc.w += fmaxf(a.w + bf.w, 0.f);
        c += 1.f;
    }
    if (gcur >= 0) {
        float* dst = pooled + gcur * F + f4;
        atomicAdd(dst + 0, acc.x); atomicAdd(dst + 1, acc.y);
        atomicAdd(dst + 2, acc.z); atomicAdd(dst + 3, acc.w);
        if (f4 == 0) atomicAdd(&cnt[gcur], c);
    }
}

// ---------------------------------------------------------------------------
// Head: out[g][c] = (sum_f pooled[g][f] * Wl[f][c]) / max(cnt[g],1) + bl[c]
__global__ void head_kernel(const float* __restrict__ pooled,
                            const float* __restrict__ cnt,
                            const float* __restrict__ Wl,
                            const float* __restrict__ bl,
                            float* __restrict__ out) {
    int tid = threadIdx.x;
    if (tid >= N_GRAPHS * N_CLASSES) return;
    int g = tid / N_CLASSES, c = tid % N_CLASSES;
    float acc = 0.f;
    for (int ff = 0; ff < F; ++ff)
        acc += pooled[g * F + ff] * Wl[ff * N_CLASSES + c];
    out[g * N_CLASSES + c] = acc / fmaxf(cnt[g], 1.f) + bl[c];
}

// ---------------------------------------------------------------------------
extern "C" void kernel_launch(void* const* d_in, const int* in_sizes, int n_in,
                              void* d_out, int out_size, void* d_ws, size_t ws_size,
                              hipStream_t stream) {
    const float* x    = (const float*)d_in[0];
    const int*   ei   = (const int*)d_in[1];     // [2][E]
    const int*   bat  = (const int*)d_in[2];
    const float* W1   = (const float*)d_in[3];
    const float* b1   = (const float*)d_in[4];
    const float* W2   = (const float*)d_in[5];
    const float* b2   = (const float*)d_in[6];
    const float* W3   = (const float*)d_in[7];
    const float* b3   = (const float*)d_in[8];
    const float* Wl   = (const float*)d_in[9];
    const float* bl   = (const float*)d_in[10];
    float* out = (float*)d_out;

    const int* row = ei;                 // edge_index[0] (source)
    const int* col = ei + N_EDGES;       // edge_index[1] (target)

    // Workspace layout (16B-aligned chunks)
    float*          ws      = (float*)d_ws;
    float*          dis     = ws;                                     // 40000 f
    unsigned short* Hb      = (unsigned short*)(dis + N_NODES);       // 5.12M bf16
    float*          AGG     = (float*)(Hb + (size_t)N_NODES * F);     // 5.12M f
    float*          pooled  = AGG + (size_t)N_NODES * F;              // 8192 f
    float*          cnt     = pooled + N_GRAPHS * F;                  // 64 f
    int*            deg     = (int*)(cnt + N_GRAPHS);                 // 40000 i
    int*            rowptr  = deg + N_NODES;                          // 40000 i
    int*            cursor  = rowptr + N_NODES;                       // 40000 i
    int*            csr_src = cursor + N_NODES;                       // 640000 i
    unsigned short* Wtb     = (unsigned short*)(csr_src + N_EDGES);   // 3*16384 bf16

    const int edgeGrid   = (N_EDGES + 255) / 256;      // 2500
    const int gemmGrid   = N_NODES / 64;               // 625
    const int gatherGrid = (N_NODES * 64) / 256;       // 10000

    hipMemsetAsync(deg, 0, N_NODES * sizeof(int), stream);
    wcvt_kernel<<<192, 256, 0, stream>>>(W1, W2, W3, Wtb);

    // --- layer 1 GEMM (unscaled bf16 H, fused degree count), then CSR build ---
    gemm_mfma<false, false, true><<<gemmGrid, 256, 0, stream>>>(
        x, Wtb, nullptr, nullptr, Hb, col, deg);
    scan_kernel<<<1, 1024, 0, stream>>>(deg, rowptr, cursor, dis);
    fill_kernel<<<edgeGrid, 256, 0, stream>>>(row, col, cursor, csr_src);
    gather_kernel<true><<<gatherGrid, 256, 0, stream>>>(Hb, csr_src, rowptr, deg, dis, AGG);

    // --- layer 2 (relu(agg+b1) fused into staging; H pre-scaled by dis) ---
    gemm_mfma<true, true, false><<<gemmGrid, 256, 0, stream>>>(
        AGG, Wtb + 16384, b1, dis, Hb, nullptr, nullptr);
    gather_kernel<false><<<gatherGrid, 256, 0, stream>>>(Hb, csr_src, rowptr, deg, dis, AGG);

    // --- layer 3 ---
    gemm_mfma<true, true, false><<<gemmGrid, 256, 0, stream>>>(
        AGG, Wtb + 32768, b2, dis, Hb, nullptr, nullptr);
    gather_kernel<false><<<gatherGrid, 256, 0, stream>>>(Hb, csr_src, rowptr, deg, dis, AGG);

    // --- pool (fuses relu(agg + b3)) + head ---
    hipMemsetAsync(pooled, 0, (N_GRAPHS * F + N_GRAPHS) * sizeof(float), stream);
    pool_kernel<<<N_NODES / POOL_NODES, 256, 0, stream>>>(AGG, bat, b3, pooled, cnt);
    head_kernel<<<1, N_GRAPHS * N_CLASSES, 0, stream>>>(pooled, cnt, Wl, bl, out);
}

// Round 7
// 304.830 us; speedup vs baseline: 12.1416x; 1.0096x over previous
//
#include <hip/hip_runtime.h>
#include <hip/hip_bf16.h>

// Problem constants (from reference)
#define N_NODES   40000
#define N_EDGES   640000
#define F         128      // F_IN == HID == 128
#define N_GRAPHS  64
#define N_CLASSES 10

typedef short bf16x8 __attribute__((ext_vector_type(8)));
typedef float f32x4  __attribute__((ext_vector_type(4)));

// fp32 -> bf16 with round-to-nearest-even
__device__ __forceinline__ unsigned short f2bf(float f) {
    union { float f; unsigned u; } v; v.f = f;
    unsigned r = v.u + 0x7fffu + ((v.u >> 16) & 1u);
    return (unsigned short)(r >> 16);
}
__device__ __forceinline__ float bflo(unsigned u) { return __uint_as_float(u << 16); }
__device__ __forceinline__ float bfhi(unsigned u) { return __uint_as_float(u & 0xffff0000u); }
__device__ __forceinline__ unsigned pack2(float a, float b) {
    return (unsigned)f2bf(a) | ((unsigned)f2bf(b) << 16);
}

// ---------------------------------------------------------------------------
// Precompute transposed bf16 weights: Wt_l[c][k] = bf16(W_l[k][c]), l=0..2.
__global__ void wcvt_kernel(const float* __restrict__ W1, const float* __restrict__ W2,
                            const float* __restrict__ W3, unsigned short* __restrict__ Wt) {
    int idx = blockIdx.x * 256 + threadIdx.x;          // 0 .. 3*16384-1
    int l = idx >> 14;
    int r = idx & 16383;
    int c = r >> 7, k = r & 127;
    const float* W = (l == 0) ? W1 : ((l == 1) ? W2 : W3);
    Wt[idx] = f2bf(W[k * 128 + c]);                    // write coalesced (k fast)
}

// ---------------------------------------------------------------------------
// CSR build step 2: single-block scan of deg -> rowptr & cursor, plus
// dis[v] = rsqrt(deg[v] + 1). Coalesced tiles of 4096 (1024 threads x int4).
__global__ __launch_bounds__(1024) void scan_kernel(
    const int* __restrict__ deg, int* __restrict__ rowptr,
    int* __restrict__ cursor, float* __restrict__ dis) {
    __shared__ int wsum[16];
    __shared__ int tile_total_s;
    const int tid  = threadIdx.x;
    const int lane = tid & 63;
    const int wave = tid >> 6;
    int running = 0;

    for (int t = 0; t < 10; ++t) {
        const int base = t * 4096 + tid * 4;
        int4 d = make_int4(0, 0, 0, 0);
        if (base < N_NODES) d = *(const int4*)(deg + base);
        const int sown = d.x + d.y + d.z + d.w;

        int s = sown;
#pragma unroll
        for (int off = 1; off < 64; off <<= 1) {
            int n = __shfl_up(s, off, 64);
            if (lane >= off) s += n;
        }
        if (lane == 63) wsum[wave] = s;
        __syncthreads();

        if (wave == 0) {
            int v = (lane < 16) ? wsum[lane] : 0;
#pragma unroll
            for (int off = 1; off < 16; off <<= 1) {
                int n = __shfl_up(v, off, 64);
                if (lane >= off) v += n;
            }
            if (lane < 16) wsum[lane] = v;
            if (lane == 15) tile_total_s = v;
        }
        __syncthreads();

        int excl = running + (wave ? wsum[wave - 1] : 0) + (s - sown);
        if (base < N_NODES) {
            int4 r;
            r.x = excl;
            r.y = r.x + d.x;
            r.z = r.y + d.y;
            r.w = r.z + d.z;
            *(int4*)(rowptr + base) = r;
            *(int4*)(cursor + base) = r;
            float4 di;
            di.x = rsqrtf((float)d.x + 1.0f);
            di.y = rsqrtf((float)d.y + 1.0f);
            di.z = rsqrtf((float)d.z + 1.0f);
            di.w = rsqrtf((float)d.w + 1.0f);
            *(float4*)(dis + base) = di;
        }
        running += tile_total_s;
        __syncthreads();
    }
}

// CSR build step 3: csr_src[cursor[col[e]]++] = row[e]
__global__ void fill_kernel(const int* __restrict__ row, const int* __restrict__ col,
                            int* __restrict__ cursor, int* __restrict__ csr_src) {
    int e = blockIdx.x * 256 + threadIdx.x;
    if (e < N_EDGES) {
        int pos = atomicAdd(&cursor[col[e]], 1);
        csr_src[pos] = row[e];
    }
}

// ---------------------------------------------------------------------------
// MFMA GEMM: Hb[r][c] = bf16( scale_r * relu?(A[r][:] + bias) @ W )
// A is fp32 (ABF16=false, layer 1) or bf16 (ABF16=true, layers 2/3, = AGGb).
// Wt = precomputed W^T bf16 [128 c][128 k]. Block: 256 threads / 4 waves,
// 64 rows. LDS 52 KB -> 3 blocks/CU.
// Fragment maps (verified m89/m92/m120): A: m=lane&15, k=quad*8+j;
// B^T: n=lane&15, k=quad*8+j; D: col=lane&15, row=quad*4+reg.
#define APITCH 136   // bf16 units; 272 B rows: 16B-aligned frags, bank-spread
template<bool ABF16, bool RELU, bool SCALE, bool COUNT>
__global__ __launch_bounds__(256) void gemm_mfma(
    const void* __restrict__ Araw, const unsigned short* __restrict__ Wt,
    const float* __restrict__ bias, const float* __restrict__ dis,
    unsigned short* __restrict__ Hb,
    const int* __restrict__ cnt_col, int* __restrict__ cnt_deg) {
    __shared__ unsigned short As[64 * APITCH];    // 17408 B
    __shared__ unsigned short Ws[128 * APITCH];   // 34816 B
    const int tid  = threadIdx.x;
    const int row0 = blockIdx.x * 64;

    if (COUNT) {   // fused degree count for CSR build (deg pre-zeroed)
        int t = (blockIdx.x * 256 + tid) * 4;
#pragma unroll
        for (int j = 0; j < 4; ++j) atomicAdd(&cnt_deg[cnt_col[t + j]], 1);
    }

    // Stage Wt (bf16, 32768 B = 2048 uint4) -> Ws
    {
        const uint4* src = (const uint4*)Wt;
#pragma unroll
        for (int j = 0; j < 8; ++j) {
            int c4 = tid + j * 256;        // 0..2047; 16 uint4 per 128-bf16 row
            int c  = c4 >> 4;
            int o  = c4 & 15;
            *(uint4*)(Ws + c * APITCH + o * 8) = src[c4];
        }
    }
    // Stage A -> bias/relu -> bf16 -> As
    if (ABF16) {
        const uint4* src = (const uint4*)Araw;     // 16 uint4 per 128-bf16 row
#pragma unroll
        for (int j = 0; j < 4; ++j) {
            int c4 = tid + j * 256;        // 0..1023
            int r  = c4 >> 4;
            int p  = c4 & 15;
            int o  = p << 3;               // bf16 col offset (8 per chunk)
            uint4 hv = src[(size_t)(row0 + r) * 16 + p];
            float f0 = bflo(hv.x), f1 = bfhi(hv.x), f2 = bflo(hv.y), f3 = bfhi(hv.y);
            float f4_ = bflo(hv.z), f5 = bfhi(hv.z), f6 = bflo(hv.w), f7 = bfhi(hv.w);
            if (bias) {
                float4 b0 = *(const float4*)(bias + o);
                float4 b1 = *(const float4*)(bias + o + 4);
                f0 += b0.x; f1 += b0.y; f2 += b0.z; f3 += b0.w;
                f4_ += b1.x; f5 += b1.y; f6 += b1.z; f7 += b1.w;
            }
            if (RELU) {
                f0 = fmaxf(f0, 0.f); f1 = fmaxf(f1, 0.f); f2 = fmaxf(f2, 0.f);
                f3 = fmaxf(f3, 0.f); f4_ = fmaxf(f4_, 0.f); f5 = fmaxf(f5, 0.f);
                f6 = fmaxf(f6, 0.f); f7 = fmaxf(f7, 0.f);
            }
            uint4 pk;
            pk.x = pack2(f0, f1); pk.y = pack2(f2, f3);
            pk.z = pack2(f4_, f5); pk.w = pack2(f6, f7);
            *(uint4*)(As + r * APITCH + o) = pk;
        }
    } else {
        const float* A = (const float*)Araw;
#pragma unroll
        for (int j = 0; j < 8; ++j) {
            int c4 = tid + j * 256;            // 0..2047; 32 float4 per row
            int r  = c4 >> 5;
            int o  = (c4 & 31) << 2;
            float4 v = *(const float4*)(A + (size_t)(row0 + r) * F + o);
            if (bias) {
                v.x += bias[o + 0]; v.y += bias[o + 1];
                v.z += bias[o + 2]; v.w += bias[o + 3];
            }
            if (RELU) {
                v.x = fmaxf(v.x, 0.f); v.y = fmaxf(v.y, 0.f);
                v.z = fmaxf(v.z, 0.f); v.w = fmaxf(v.w, 0.f);
            }
            uint2 p;
            p.x = pack2(v.x, v.y);
            p.y = pack2(v.z, v.w);
            *(uint2*)(As + r * APITCH + o) = p;
        }
    }
    __syncthreads();

    const int lane = tid & 63;
    const int wave = tid >> 6;
    const int m16  = lane & 15;
    const int quad = lane >> 4;

    f32x4 acc[8];
#pragma unroll
    for (int t = 0; t < 8; ++t) acc[t] = (f32x4)(0.0f);

#pragma unroll
    for (int ks = 0; ks < 128; ks += 32) {
        bf16x8 a = *(const bf16x8*)(As + (wave * 16 + m16) * APITCH + ks + quad * 8);
#pragma unroll
        for (int t = 0; t < 8; ++t) {
            bf16x8 b = *(const bf16x8*)(Ws + (t * 16 + m16) * APITCH + ks + quad * 8);
            acc[t] = __builtin_amdgcn_mfma_f32_16x16x32_bf16(a, b, acc[t], 0, 0, 0);
        }
    }

    // Epilogue: D row = quad*4+reg, col = t*16 + m16; optional dis[row] scale.
    const int rbase = row0 + wave * 16 + quad * 4;
    float sc[4];
#pragma unroll
    for (int rg = 0; rg < 4; ++rg) sc[rg] = SCALE ? dis[rbase + rg] : 1.0f;
#pragma unroll
    for (int t = 0; t < 8; ++t) {
        int col = t * 16 + m16;
#pragma unroll
        for (int rg = 0; rg < 4; ++rg)
            Hb[(size_t)(rbase + rg) * F + col] = f2bf(acc[t][rg] * sc[rg]);
    }
}

// ---------------------------------------------------------------------------
// Gather aggregation v5 (bf16 H -> bf16 AGG): one wave per node; 16 edges per
// step with 4 independent uint4 gathers in flight per lane (masked; avg degree
// 16 -> typically one step); fp32 accumulate, quad shfl_xor reduction.
// SCALED=false: Hb pre-scaled by dis[row]:  AGG[v] = dis[v]*(sum Hb[src] + Hb[v])
// SCALED=true : AGG[v] = dis[v]*(sum dis[src]*Hb[src] + dis[v]*Hb[v])
template <bool SCALED>
__global__ __launch_bounds__(256) void gather_kernel(
    const unsigned short* __restrict__ Hb, const int* __restrict__ csr_src,
    const int* __restrict__ rowptr, const int* __restrict__ deg,
    const float* __restrict__ dis, unsigned short* __restrict__ AGGb) {
    const int gid  = blockIdx.x * 256 + threadIdx.x;
    const int v    = gid >> 6;
    if (v >= N_NODES) return;
    const int lane = threadIdx.x & 63;
    const int part = lane & 15;          // 16B chunk of the 256B row
    const int quad = lane >> 4;          // edge slot within group of 4

    const int start = rowptr[v];
    const int len   = deg[v];
    const uint4* Hp = (const uint4*)Hb + part;   // 16 uint4 per row

    float acc[8];
#pragma unroll
    for (int i = 0; i < 8; ++i) acc[i] = 0.f;

    for (int j0 = 0; j0 < len; j0 += 64) {
        int m = len - j0; if (m > 64) m = 64;
        int nidx = (lane < m) ? csr_src[start + j0 + lane] : 0;
        for (int j = 0; j < m; j += 16) {
            int   r[4];
            float w[4];
            uint4 h[4];
#pragma unroll
            for (int u = 0; u < 4; ++u) {
                int  sl    = j + u * 4 + quad;
                bool valid = sl < m;
                r[u] = __shfl(nidx, valid ? sl : 0, 64);
                w[u] = valid ? (SCALED ? dis[r[u]] : 1.0f) : 0.0f;
            }
#pragma unroll
            for (int u = 0; u < 4; ++u) h[u] = Hp[(size_t)r[u] * 16];
#pragma unroll
            for (int u = 0; u < 4; ++u) {
                acc[0] = fmaf(bflo(h[u].x), w[u], acc[0]);
                acc[1] = fmaf(bfhi(h[u].x), w[u], acc[1]);
                acc[2] = fmaf(bflo(h[u].y), w[u], acc[2]);
                acc[3] = fmaf(bfhi(h[u].y), w[u], acc[3]);
                acc[4] = fmaf(bflo(h[u].z), w[u], acc[4]);
                acc[5] = fmaf(bfhi(h[u].z), w[u], acc[5]);
                acc[6] = fmaf(bflo(h[u].w), w[u], acc[6]);
                acc[7] = fmaf(bfhi(h[u].w), w[u], acc[7]);
            }
        }
    }

    // combine the 4 edge-slots (same cols at lane^16, lane^32)
#pragma unroll
    for (int i = 0; i < 8; ++i) {
        acc[i] += __shfl_xor(acc[i], 16, 64);
        acc[i] += __shfl_xor(acc[i], 32, 64);
    }

    if (quad == 0) {
        float dc  = dis[v];
        float ws_ = SCALED ? dc : 1.0f;
        uint4 h = Hp[(size_t)v * 16];               // self-loop
        acc[0] = fmaf(bflo(h.x), ws_, acc[0]); acc[1] = fmaf(bfhi(h.x), ws_, acc[1]);
        acc[2] = fmaf(bflo(h.y), ws_, acc[2]); acc[3] = fmaf(bfhi(h.y), ws_, acc[3]);
        acc[4] = fmaf(bflo(h.z), ws_, acc[4]); acc[5] = fmaf(bfhi(h.z), ws_, acc[5]);
        acc[6] = fmaf(bflo(h.w), ws_, acc[6]); acc[7] = fmaf(bfhi(h.w), ws_, acc[7]);
        uint4 pk;
        pk.x = pack2(acc[0] * dc, acc[1] * dc);
        pk.y = pack2(acc[2] * dc, acc[3] * dc);
        pk.z = pack2(acc[4] * dc, acc[5] * dc);
        pk.w = pack2(acc[6] * dc, acc[7] * dc);
        *((uint4*)AGGb + (size_t)v * 16 + part) = pk;
    }
}

// ---------------------------------------------------------------------------
// Pool v3 (bf16 AGG): 400 blocks x 100 nodes; 8 row-slots x 32 lanes x 4 cols.
// pooled[g][f] += relu(AGG[v][f] + b3[f]); cnt[g] += 1. batch sorted ->
// per-slot run-length accumulate (slot's g non-decreasing), flush on change.
#define POOL_NODES 100
__global__ __launch_bounds__(256) void pool_kernel(
    const unsigned short* __restrict__ AGGb, const int* __restrict__ batch,
    const float* __restrict__ b3,
    float* __restrict__ pooled, float* __restrict__ cnt) {
    const int tid  = threadIdx.x;
    const int f4   = (tid & 31) << 2;     // 4-col group
    const int slot = tid >> 5;            // 0..7
    const int base = blockIdx.x * POOL_NODES;
    const float4 bf = *(const float4*)(b3 + f4);

    float4 acc = make_float4(0.f, 0.f, 0.f, 0.f);
    float c = 0.f;
    int gcur = -1;
    for (int j = slot; j < POOL_NODES; j += 8) {
        int v = base + j;                 // 400*100 = 40000, always in range
        int g = batch[v];
        if (g != gcur) {
            if (gcur >= 0) {
                float* dst = pooled + gcur * F + f4;
                atomicAdd(dst + 0, acc.x); atomicAdd(dst + 1, acc.y);
                atomicAdd(dst + 2, acc.z); atomicAdd(dst + 3, acc.w);
                if (f4 == 0) atomicAdd(&cnt[gcur], c);
            }
            acc = make_float4(0.f, 0.f, 0.f, 0.f); c = 0.f; gcur = g;
        }
        uint2 a = *(const uint2*)(AGGb + (size_t)v * F + f4);
        acc.x += fmaxf(bflo(a.x) + bf.x, 0.f);
        acc.y += fmaxf(bfhi(a.x) + bf.y, 0.f);
        acc.z += fmaxf(bflo(a.y) + bf.z, 0.f);
        acc.w += fmaxf(bfhi(a.y) + bf.w, 0.f);
        c += 1.f;
    }
    if (gcur >= 0) {
        float* dst = pooled + gcur * F + f4;
        atomicAdd(dst + 0, acc.x); atomicAdd(dst + 1, acc.y);
        atomicAdd(dst + 2, acc.z); atomicAdd(dst + 3, acc.w);
        if (f4 == 0) atomicAdd(&cnt[gcur], c);
    }
}

// ---------------------------------------------------------------------------
// Head: out[g][c] = (sum_f pooled[g][f] * Wl[f][c]) / max(cnt[g],1) + bl[c]
__global__ void head_kernel(const float* __restrict__ pooled,
                            const float* __restrict__ cnt,
                            const float* __restrict__ Wl,
                            const float* __restrict__ bl,
                            float* __restrict__ out) {
    int tid = threadIdx.x;
    if (tid >= N_GRAPHS * N_CLASSES) return;
    int g = tid / N_CLASSES, c = tid % N_CLASSES;
    float acc = 0.f;
    for (int ff = 0; ff < F; ++ff)
        acc += pooled[g * F + ff] * Wl[ff * N_CLASSES + c];
    out[g * N_CLASSES + c] = acc / fmaxf(cnt[g], 1.f) + bl[c];
}

// ---------------------------------------------------------------------------
extern "C" void kernel_launch(void* const* d_in, const int* in_sizes, int n_in,
                              void* d_out, int out_size, void* d_ws, size_t ws_size,
                              hipStream_t stream) {
    const float* x    = (const float*)d_in[0];
    const int*   ei   = (const int*)d_in[1];     // [2][E]
    const int*   bat  = (const int*)d_in[2];
    const float* W1   = (const float*)d_in[3];
    const float* b1   = (const float*)d_in[4];
    const float* W2   = (const float*)d_in[5];
    const float* b2   = (const float*)d_in[6];
    const float* W3   = (const float*)d_in[7];
    const float* b3   = (const float*)d_in[8];
    const float* Wl   = (const float*)d_in[9];
    const float* bl   = (const float*)d_in[10];
    float* out = (float*)d_out;

    const int* row = ei;                 // edge_index[0] (source)
    const int* col = ei + N_EDGES;       // edge_index[1] (target)

    // Workspace layout (16B-aligned chunks)
    float*          ws      = (float*)d_ws;
    float*          dis     = ws;                                     // 40000 f
    unsigned short* Hb      = (unsigned short*)(dis + N_NODES);       // 5.12M bf16
    unsigned short* AGGb    = Hb + (size_t)N_NODES * F;               // 5.12M bf16
    float*          pooled  = (float*)(AGGb + (size_t)N_NODES * F);   // 8192 f
    float*          cnt     = pooled + N_GRAPHS * F;                  // 64 f
    int*            deg     = (int*)(cnt + N_GRAPHS);                 // 40000 i
    int*            rowptr  = deg + N_NODES;                          // 40000 i
    int*            cursor  = rowptr + N_NODES;                       // 40000 i
    int*            csr_src = cursor + N_NODES;                       // 640000 i
    unsigned short* Wtb     = (unsigned short*)(csr_src + N_EDGES);   // 3*16384 bf16

    const int edgeGrid   = (N_EDGES + 255) / 256;      // 2500
    const int gemmGrid   = N_NODES / 64;               // 625
    const int gatherGrid = (N_NODES * 64) / 256;       // 10000

    hipMemsetAsync(deg, 0, N_NODES * sizeof(int), stream);
    wcvt_kernel<<<192, 256, 0, stream>>>(W1, W2, W3, Wtb);

    // --- layer 1 GEMM (unscaled bf16 H, fused degree count), then CSR build ---
    gemm_mfma<false, false, false, true><<<gemmGrid, 256, 0, stream>>>(
        x, Wtb, nullptr, nullptr, Hb, col, deg);
    scan_kernel<<<1, 1024, 0, stream>>>(deg, rowptr, cursor, dis);
    fill_kernel<<<edgeGrid, 256, 0, stream>>>(row, col, cursor, csr_src);
    gather_kernel<true><<<gatherGrid, 256, 0, stream>>>(Hb, csr_src, rowptr, deg, dis, AGGb);

    // --- layer 2 (relu(agg+b1) fused into staging; H pre-scaled by dis) ---
    gemm_mfma<true, true, true, false><<<gemmGrid, 256, 0, stream>>>(
        AGGb, Wtb + 16384, b1, dis, Hb, nullptr, nullptr);
    gather_kernel<false><<<gatherGrid, 256, 0, stream>>>(Hb, csr_src, rowptr, deg, dis, AGGb);

    // --- layer 3 ---
    gemm_mfma<true, true, true, false><<<gemmGrid, 256, 0, stream>>>(
        AGGb, Wtb + 32768, b2, dis, Hb, nullptr, nullptr);
    gather_kernel<false><<<gatherGrid, 256, 0, stream>>>(Hb, csr_src, rowptr, deg, dis, AGGb);

    // --- pool (fuses relu(agg + b3)) + head ---
    hipMemsetAsync(pooled, 0, (N_GRAPHS * F + N_GRAPHS) * sizeof(float), stream);
    pool_kernel<<<N_NODES / POOL_NODES, 256, 0, stream>>>(AGGb, bat, b3, pooled, cnt);
    head_kernel<<<1, N_GRAPHS * N_CLASSES, 0, stream>>>(pooled, cnt, Wl, bl, out);
}